// Round 9
// baseline (444.383 us; speedup 1.0000x reference)
//
#include <hip/hip_runtime.h>
#include <hip/hip_bf16.h>

#define N_NODES 50000
#define N_EDGES 500000
#define N_REL   50
#define NTILES  ((N_EDGES + 63) / 64)   // 7813
#define EBLOCKS 1280
#define NODE_TILES ((N_NODES + 63) / 64)  // 782

// workspace layout (float-sized slots)
#define CNTI_OFF   0                          // int[50000]  (memset to 0)
#define STARTS_OFF (CNTI_OFF + N_NODES)
#define CURSOR_OFF (STARTS_OFF + N_NODES)
#define SRCB_OFF   (CURSOR_OFF + N_NODES)     // int[500000] src grouped by dst
#define PRB_OFF    (SRCB_OFF + N_EDGES)       // short[50000*128] (bf16)
#define H1_OFF     (PRB_OFF + N_NODES*32)     // short[50000*64]  (bf16)
#define PLB_OFF    (H1_OFF + N_NODES*32)      // short[50000*128] (bf16)
// end = PLB_OFF + N_NODES*32 = 8.65M floats = 34.6 MB

typedef short short8  __attribute__((ext_vector_type(8)));
typedef short short4v __attribute__((ext_vector_type(4)));
typedef float f32x4   __attribute__((ext_vector_type(4)));
typedef float f4      __attribute__((ext_vector_type(4)));

#define MFMA16(a,b,c) __builtin_amdgcn_mfma_f32_16x16x32_bf16((a),(b),(c),0,0,0)

__device__ __forceinline__ short f2bf(float x) {
    unsigned u = __float_as_uint(x);
    unsigned r = (u + 0x7fffu + ((u >> 16) & 1u)) >> 16;   // RNE
    return (short)r;
}
__device__ __forceinline__ float bf2f(short s) {
    return __uint_as_float(((unsigned)(unsigned short)s) << 16);
}

__device__ __forceinline__ short8 load_wfrag(const float* __restrict__ W, int row, int K, int k) {
    const f4* p = (const f4*)(W + (size_t)row * K + k);
    f4 a = p[0], b = p[1];
    short8 r;
    r[0] = f2bf(a[0]); r[1] = f2bf(a[1]); r[2] = f2bf(a[2]); r[3] = f2bf(a[3]);
    r[4] = f2bf(b[0]); r[5] = f2bf(b[1]); r[6] = f2bf(b[2]); r[7] = f2bf(b[3]);
    return r;
}

// ---------------- CSR build ----------------

// hist of dst + y->out copy (nt store: out never read)
__global__ __launch_bounds__(256) void k_histy(
    const int* __restrict__ dst, int* __restrict__ cnt_i,
    const int* __restrict__ y, float* __restrict__ out)
{
    int e = blockIdx.x * blockDim.x + threadIdx.x;
    if (e < N_EDGES) {
        atomicAdd(&cnt_i[dst[e]], 1);
        __builtin_nontemporal_store((float)y[e], &out[(size_t)N_EDGES * N_REL + e]);
    }
}

__global__ __launch_bounds__(1024) void k_scan(
    const int* __restrict__ cnt_i, int* __restrict__ starts, int* __restrict__ cursor)
{
    __shared__ int part[1024];
    const int i  = threadIdx.x;
    const int lo = i * 49;
    const int hi = min(N_NODES, lo + 49);
    int s = 0;
    for (int j = lo; j < hi; ++j) s += cnt_i[j];
    part[i] = s;
    __syncthreads();
    for (int d = 1; d < 1024; d <<= 1) {
        int v = (i >= d) ? part[i - d] : 0;
        __syncthreads();
        part[i] += v;
        __syncthreads();
    }
    int off = (i == 0) ? 0 : part[i - 1];
    for (int j = lo; j < hi; ++j) {
        starts[j] = off;
        cursor[j] = off;
        off += cnt_i[j];
    }
}

__global__ __launch_bounds__(256) void k_bucket(
    const int* __restrict__ src, const int* __restrict__ dst,
    int* __restrict__ cursor, int* __restrict__ srcb)
{
    int e = blockIdx.x * blockDim.x + threadIdx.x;
    if (e < N_EDGES) {
        int pos = atomicAdd(&cursor[dst[e]], 1);
        srcb[pos] = src[e];
    }
}

// ---------------- SAGE1 with fused in-edge gather ----------------
__global__ __launch_bounds__(256) void k_sage1g(
    const float* __restrict__ x, const int* __restrict__ srcb,
    const int* __restrict__ starts, const int* __restrict__ cnt_i,
    const float* __restrict__ w1_l, const float* __restrict__ b1,
    const float* __restrict__ w1_r, short* __restrict__ h1b)
{
    __shared__ short feat[64 * 40];

    const int t    = threadIdx.x;
    const int w    = t >> 6;
    const int lane = t & 63;
    const int lr   = lane & 15;
    const int lg   = lane >> 4;
    const int base = blockIdx.x * 64;

    short8 w1f;
    if (lg < 2) w1f = load_wfrag(w1_l, w * 16 + lr, 16, lg * 8);
    else        w1f = load_wfrag(w1_r, w * 16 + lr, 16, (lg - 2) * 8);

    {
        int e  = t >> 2, q = t & 3;
        int ng = base + e;
        short8 v = (short8)0;
        if (ng < N_NODES) {
            if (q < 2) {
                int st = starts[ng], c = cnt_i[ng];
                float acc[8] = {0, 0, 0, 0, 0, 0, 0, 0};
                for (int i = 0; i < c; ++i) {
                    const float* xp = x + (size_t)srcb[st + i] * 16 + q * 8;
                    f4 a = *(const f4*)xp;
                    f4 b = *(const f4*)(xp + 4);
#pragma unroll
                    for (int j = 0; j < 4; ++j) { acc[j] += a[j]; acc[4 + j] += b[j]; }
                }
                float inv = 1.0f / (float)(c > 0 ? c : 1);
#pragma unroll
                for (int j = 0; j < 8; ++j) v[j] = f2bf(acc[j] * inv);
            } else {
                f4 a = *(const f4*)(x + (size_t)ng * 16 + (q - 2) * 8);
                f4 b = *(const f4*)(x + (size_t)ng * 16 + (q - 2) * 8 + 4);
#pragma unroll
                for (int j = 0; j < 4; ++j) { v[j] = f2bf(a[j]); v[4 + j] = f2bf(b[j]); }
            }
        }
        *(short8*)&feat[e * 40 + q * 8] = v;
    }
    __syncthreads();

    f32x4 acc[4];
    f4 bia = *(const f4*)&b1[w * 16 + lg * 4];
#pragma unroll
    for (int nt = 0; nt < 4; ++nt) {
        acc[nt][0] = bia[0]; acc[nt][1] = bia[1]; acc[nt][2] = bia[2]; acc[nt][3] = bia[3];
    }
#pragma unroll
    for (int nt = 0; nt < 4; ++nt) {
        int e = nt * 16 + lr;
        short8 bf = *(const short8*)&feat[e * 40 + lg * 8];
        acc[nt] = MFMA16(w1f, bf, acc[nt]);
    }
#pragma unroll
    for (int nt = 0; nt < 4; ++nt) {
        int ng = base + nt * 16 + lr;
        if (ng < N_NODES) {
            short4v o;
#pragma unroll
            for (int r = 0; r < 4; ++r) { float v = acc[nt][r]; o[r] = f2bf(v > 0.0f ? v : 0.0f); }
            *(short4v*)&h1b[(size_t)ng * 64 + w * 16 + lg * 4] = o;
        }
    }
}

// ---------------- SAGE2 + proj, with 4-way-parallel fused gather ------------
// Staging thread (e, q): ALL 4 threads gather partial mean sums:
//   feat-half = q&1 (32 feats), edge-parity = q>>1 (edges i%2==par).
// q>=2 threads park partials in pscr (=feat2 memory, dead until phase A),
// wave-local combine by q<2 threads (+inv scale, bf16, swizzled K[64,128));
// q>=2 threads then stage self-h1 into K[0,64). 2x parallelism on the
// serial degree loop vs round 8.
__global__ __launch_bounds__(256) void k_sage2g(
    const short* __restrict__ h1b, const int* __restrict__ srcb,
    const int* __restrict__ starts, const int* __restrict__ cnt_i,
    const float* __restrict__ w2_l, const float* __restrict__ b2,
    const float* __restrict__ w2_r, const float* __restrict__ ow1,
    short* __restrict__ plb, short* __restrict__ prb)
{
    __shared__ short feat[64 * 128];
    __shared__ short feat2[64 * 128];   // phase-A output; pscr scratch before that

    const int t    = threadIdx.x;
    const int w    = t >> 6;
    const int lane = t & 63;
    const int lr   = lane & 15;
    const int lg   = lane >> 4;
    const int base = blockIdx.x * 64;

    short8 wf[2][4];
#pragma unroll
    for (int mt = 0; mt < 2; ++mt)
#pragma unroll
        for (int kt = 0; kt < 4; ++kt) {
            int row = w * 32 + mt * 16 + lr;
            int k   = kt * 32 + lg * 8;
            wf[mt][kt] = (k < 64) ? load_wfrag(w2_r, row, 64, k)
                                  : load_wfrag(w2_l, row, 64, k - 64);
        }

    {
        int e = t >> 2, q = t & 3;
        int ng = base + e;
        int half = q & 1;          // feat half (32 feats)
        int par  = q >> 1;         // edge parity
        float acc[32];
#pragma unroll
        for (int j = 0; j < 32; ++j) acc[j] = 0.0f;
        int c = 0;
        if (ng < N_NODES) {
            int st = starts[ng];
            c = cnt_i[ng];
            for (int i = par; i < c; i += 2) {
                const short8* hp = (const short8*)(h1b + (size_t)srcb[st + i] * 64 + half * 32);
                short8 a0 = hp[0], a1 = hp[1], a2 = hp[2], a3 = hp[3];
#pragma unroll
                for (int j = 0; j < 8; ++j) {
                    acc[j]      += bf2f(a0[j]);
                    acc[8 + j]  += bf2f(a1[j]);
                    acc[16 + j] += bf2f(a2[j]);
                    acc[24 + j] += bf2f(a3[j]);
                }
            }
        }
        float* pscr = (float*)feat2;   // [64 nodes][64 feats]
        if (q >= 2) {
#pragma unroll
            for (int j = 0; j < 32; ++j) pscr[e * 64 + half * 32 + j] = acc[j];
        }
        __builtin_amdgcn_wave_barrier();   // node's 4 threads are wave-adjacent
        if (q < 2) {
            // combine parity-1 partial (same feat half) + scale + store mean
#pragma unroll
            for (int j = 0; j < 32; ++j) acc[j] += pscr[e * 64 + q * 32 + j];
            float inv = 1.0f / (float)(c > 0 ? c : 1);
#pragma unroll
            for (int jj = 0; jj < 4; ++jj) {
                short8 v;
#pragma unroll
                for (int j = 0; j < 8; ++j) v[j] = f2bf(acc[jj * 8 + j] * inv);
                int scol = (q * 32 + 64 + jj * 8) ^ ((e & 7) << 3);
                *(short8*)&feat[e * 128 + scol] = v;
            }
        } else {
            // self-h1 -> K[0,64)
            const short* hp = (ng < N_NODES) ? (h1b + (size_t)ng * 64 + (q - 2) * 32) : nullptr;
#pragma unroll
            for (int j = 0; j < 4; ++j) {
                short8 v = hp ? *(const short8*)(hp + j * 8) : (short8)0;
                int scol = ((q - 2) * 32 + j * 8) ^ ((e & 7) << 3);
                *(short8*)&feat[e * 128 + scol] = v;
            }
        }
    }
    __syncthreads();   // feat ready; pscr (feat2) dead

    // phase A: h2 tile (bf16, swizzled, LDS only)
    {
        f32x4 acc[2][4];
#pragma unroll
        for (int mt = 0; mt < 2; ++mt) {
            f4 bia = *(const f4*)&b2[w * 32 + mt * 16 + lg * 4];
#pragma unroll
            for (int nt = 0; nt < 4; ++nt) {
                acc[mt][nt][0] = bia[0]; acc[mt][nt][1] = bia[1];
                acc[mt][nt][2] = bia[2]; acc[mt][nt][3] = bia[3];
            }
        }
#pragma unroll
        for (int kt = 0; kt < 4; ++kt) {
            short8 bf[4];
#pragma unroll
            for (int nt = 0; nt < 4; ++nt) {
                int e = nt * 16 + lr;
                int scol = (kt * 32 + lg * 8) ^ ((e & 7) << 3);
                bf[nt] = *(const short8*)&feat[e * 128 + scol];
            }
#pragma unroll
            for (int mt = 0; mt < 2; ++mt)
#pragma unroll
                for (int nt = 0; nt < 4; ++nt)
                    acc[mt][nt] = MFMA16(wf[mt][kt], bf[nt], acc[mt][nt]);
        }
#pragma unroll
        for (int mt = 0; mt < 2; ++mt)
#pragma unroll
            for (int nt = 0; nt < 4; ++nt) {
                int e  = nt * 16 + lr;
                int n0 = w * 32 + mt * 16 + lg * 4;
                short4v s;
#pragma unroll
                for (int r = 0; r < 4; ++r) {
                    float v = acc[mt][nt][r];
                    s[r] = f2bf(v > 0.0f ? v : 0.0f);
                }
                *(short4v*)&feat2[e * 128 + (n0 ^ ((e & 7) << 3))] = s;
            }
    }
    __syncthreads();

    // phase B: PL / PR projections
    short8 wfL[2][4], wfR[2][4];
#pragma unroll
    for (int mt = 0; mt < 2; ++mt)
#pragma unroll
        for (int kt = 0; kt < 4; ++kt) {
            int row = w * 32 + mt * 16 + lr;
            int k   = kt * 32 + lg * 8;
            wfL[mt][kt] = load_wfrag(ow1, row, 256, k);
            wfR[mt][kt] = load_wfrag(ow1, row, 256, 128 + k);
        }
    f32x4 aL[2][4], aR[2][4];
#pragma unroll
    for (int mt = 0; mt < 2; ++mt)
#pragma unroll
        for (int nt = 0; nt < 4; ++nt) { aL[mt][nt] = (f32x4)0.0f; aR[mt][nt] = (f32x4)0.0f; }
#pragma unroll
    for (int kt = 0; kt < 4; ++kt) {
        short8 bf[4];
#pragma unroll
        for (int nt = 0; nt < 4; ++nt) {
            int e = nt * 16 + lr;
            int scol = (kt * 32 + lg * 8) ^ ((e & 7) << 3);
            bf[nt] = *(const short8*)&feat2[e * 128 + scol];
        }
#pragma unroll
        for (int mt = 0; mt < 2; ++mt)
#pragma unroll
            for (int nt = 0; nt < 4; ++nt) {
                aL[mt][nt] = MFMA16(wfL[mt][kt], bf[nt], aL[mt][nt]);
                aR[mt][nt] = MFMA16(wfR[mt][kt], bf[nt], aR[mt][nt]);
            }
    }
#pragma unroll
    for (int mt = 0; mt < 2; ++mt)
#pragma unroll
        for (int nt = 0; nt < 4; ++nt) {
            int ng = base + nt * 16 + lr;
            if (ng < N_NODES) {
                int n0 = w * 32 + mt * 16 + lg * 4;
                short4v oL, oR;
#pragma unroll
                for (int r = 0; r < 4; ++r) { oL[r] = f2bf(aL[mt][nt][r]); oR[r] = f2bf(aR[mt][nt][r]); }
                *(short4v*)&plb[(size_t)ng * 128 + n0] = oL;
                *(short4v*)&prb[(size_t)ng * 128 + n0] = oR;
            }
        }
}

// ---------------- edge MLP v3: original order, prefetch, nt coalesced out ---
__global__ __launch_bounds__(256, 5) void k_edge3(
    const short* __restrict__ plb, const short* __restrict__ prb,
    const int* __restrict__ src, const int* __restrict__ dst,
    const float* __restrict__ ob1,
    const float* __restrict__ ow2, const float* __restrict__ ob2,
    const float* __restrict__ ow3, const float* __restrict__ ob3,
    const float* __restrict__ ow4, const float* __restrict__ ob4,
    const float* __restrict__ rw1, const float* __restrict__ rb1,
    const float* __restrict__ rw2, const float* __restrict__ rb2,
    const float* __restrict__ rw3, const float* __restrict__ rb3,
    float* __restrict__ out)
{
    __shared__ short a1s[64 * 128];    // 16KB; tail T aliases
    __shared__ short actB[64 * 96];    // act2 | act3
    __shared__ float sw[662];

    short* act2  = actB;
    short* act3  = actB + 64 * 64;
    float* tailf = (float*)a1s;

    const int t    = threadIdx.x;
    const int w    = t >> 6;
    const int lane = t & 63;
    const int lr   = lane & 15;
    const int lg   = lane >> 4;

    if (t < 128) sw[t]       = ob1[t];
    if (t < 64)  sw[128 + t] = ob2[t];
    if (t < 32)  sw[192 + t] = ob3[t];
    if (t < 16)  sw[224 + t] = ob4[t];
    if (t < 8)   sw[240 + t] = rb1[t];
    if (t < 4)   sw[248 + t] = rb2[t];
    if (t < 50)  sw[252 + t] = rb3[t];
    if (t < 128) sw[302 + t] = rw1[t];
    if (t < 32)  sw[430 + t] = rw2[t];
    if (t < 200) sw[462 + t] = rw3[t];

    short8 w2f[4];
#pragma unroll
    for (int kt = 0; kt < 4; ++kt)
        w2f[kt] = load_wfrag(ow2, w * 16 + lr, 128, kt * 32 + lg * 8);

    short8 w3f[2][2];
#pragma unroll
    for (int mt = 0; mt < 2; ++mt)
#pragma unroll
        for (int kt = 0; kt < 2; ++kt)
            w3f[mt][kt] = load_wfrag(ow3, mt * 16 + lr, 64, kt * 32 + lg * 8);

    short8 w4f = load_wfrag(ow4, lr, 32, lg * 8);

    __syncthreads();   // sw ready

    const int e = t >> 2, p = t & 3;
    short8 vl0, vl1, vl2, vl3, vr0, vr1, vr2, vr3;

#define LOADTILE(TI)                                                        \
    {                                                                       \
        int eg  = (TI) * 64 + e;                                            \
        int egc = eg < N_EDGES ? eg : N_EDGES - 1;                          \
        int sn = src[egc], dn = dst[egc];                                   \
        const short8* plp = (const short8*)(plb + (size_t)sn * 128 + p * 32); \
        const short8* prp = (const short8*)(prb + (size_t)dn * 128 + p * 32); \
        vl0 = plp[0]; vl1 = plp[1]; vl2 = plp[2]; vl3 = plp[3];             \
        vr0 = prp[0]; vr1 = prp[1]; vr2 = prp[2]; vr3 = prp[3];             \
    }

    LOADTILE(blockIdx.x)

    for (int tile = blockIdx.x; tile < NTILES; tile += EBLOCKS) {
        const int base = tile * 64;

        // ---- stage a1 = relu(PL[src] + PR[dst] + ob1), bf16, swizzled ----
        {
            short8 VL[4] = {vl0, vl1, vl2, vl3};
            short8 VR[4] = {vr0, vr1, vr2, vr3};
#pragma unroll
            for (int j = 0; j < 4; ++j) {
                short8 s;
#pragma unroll
                for (int i = 0; i < 8; ++i) {
                    float v = bf2f(VL[j][i]) + bf2f(VR[j][i]) + sw[p * 32 + j * 8 + i];
                    s[i] = f2bf(v > 0.0f ? v : 0.0f);
                }
                int scol = (p * 32 + j * 8) ^ ((e & 7) << 3);
                *(short8*)&a1s[e * 128 + scol] = s;
            }
        }
        __syncthreads();

        // ---- prefetch next tile (flies during L2 + tail) ----
        if (tile + EBLOCKS < NTILES) LOADTILE(tile + EBLOCKS)

        // ---- L2: 128 -> 64, relu ----
        {
            f32x4 acc[4];
            f32x4 bia;
#pragma unroll
            for (int r = 0; r < 4; ++r) bia[r] = sw[128 + w * 16 + lg * 4 + r];
#pragma unroll
            for (int nt = 0; nt < 4; ++nt) acc[nt] = bia;
#pragma unroll
            for (int kt = 0; kt < 4; ++kt) {
#pragma unroll
                for (int nt = 0; nt < 4; ++nt) {
                    int en = nt * 16 + lr;
                    int scol = (kt * 32 + lg * 8) ^ ((en & 7) << 3);
                    short8 bf = *(const short8*)&a1s[en * 128 + scol];
                    acc[nt] = MFMA16(w2f[kt], bf, acc[nt]);
                }
            }
#pragma unroll
            for (int nt = 0; nt < 4; ++nt) {
                int en = nt * 16 + lr;
                int n0 = w * 16 + lg * 4;
                short4v s;
#pragma unroll
                for (int r = 0; r < 4; ++r) {
                    float v = acc[nt][r];
                    s[r] = f2bf(v > 0.0f ? v : 0.0f);
                }
                *(short4v*)&act2[en * 64 + (n0 ^ ((en & 7) << 3))] = s;
            }
        }
        __syncthreads();   // act2 ready; a1s dead -> tail T may alias

        // ---- wave-local tail ----
        {
            const int e3 = w * 16 + lr;
            float* T = tailf + w * 512;

            f32x4 acc[2];
#pragma unroll
            for (int mt = 0; mt < 2; ++mt)
#pragma unroll
                for (int r = 0; r < 4; ++r) acc[mt][r] = sw[192 + mt * 16 + lg * 4 + r];
#pragma unroll
            for (int kt = 0; kt < 2; ++kt) {
                int scol = (kt * 32 + lg * 8) ^ ((e3 & 7) << 3);
                short8 bf = *(const short8*)&act2[e3 * 64 + scol];
#pragma unroll
                for (int mt = 0; mt < 2; ++mt)
                    acc[mt] = MFMA16(w3f[mt][kt], bf, acc[mt]);
            }
#pragma unroll
            for (int mt = 0; mt < 2; ++mt) {
                short4v s;
#pragma unroll
                for (int r = 0; r < 4; ++r) {
                    float v = acc[mt][r];
                    s[r] = f2bf(v > 0.0f ? v : 0.0f);
                }
                *(short4v*)&act3[e3 * 32 + mt * 16 + lg * 4] = s;
            }
            __builtin_amdgcn_wave_barrier();

            {
                short8 bf = *(const short8*)&act3[e3 * 32 + lg * 8];
                f32x4 a4;
#pragma unroll
                for (int r = 0; r < 4; ++r) a4[r] = sw[224 + lg * 4 + r];
                a4 = MFMA16(w4f, bf, a4);
#pragma unroll
                for (int r = 0; r < 4; ++r) T[lr * 17 + lg * 4 + r] = a4[r];
            }
            __builtin_amdgcn_wave_barrier();

            {
                float af[16];
#pragma unroll
                for (int f = 0; f < 16; ++f) af[f] = T[lr * 17 + f];
#pragma unroll
                for (int oo = 0; oo < 2; ++oo) {
                    int o = lg * 2 + oo;
                    float v = sw[240 + o];
#pragma unroll
                    for (int f = 0; f < 16; ++f) v += af[f] * sw[302 + o * 16 + f];
                    T[272 + lr * 9 + o] = v > 0.0f ? v : 0.0f;
                }
            }
            __builtin_amdgcn_wave_barrier();

            {
                float v = sw[248 + lg];
#pragma unroll
                for (int f = 0; f < 8; ++f) v += T[272 + lr * 9 + f] * sw[430 + lg * 8 + f];
                T[416 + lr * 5 + lg] = v > 0.0f ? v : 0.0f;
            }
            __builtin_amdgcn_wave_barrier();

            // rf3: 4 -> 50, COALESCED, non-temporal (out never read)
            size_t obase = (size_t)(base + w * 16) * N_REL;
#pragma unroll
            for (int k2 = 0; k2 < 13; ++k2) {
                int idx = k2 * 64 + lane;
                if (idx < 16 * N_REL) {
                    int el = idx / N_REL;
                    int o  = idx - el * N_REL;
                    if (base + w * 16 + el < N_EDGES) {
                        float v = sw[252 + o];
#pragma unroll
                        for (int f = 0; f < 4; ++f) v += T[416 + el * 5 + f] * sw[462 + o * 4 + f];
                        __builtin_nontemporal_store(v, &out[obase + idx]);
                    }
                }
            }
        }
        __syncthreads();
    }
#undef LOADTILE
}

extern "C" void kernel_launch(void* const* d_in, const int* in_sizes, int n_in,
                              void* d_out, int out_size, void* d_ws, size_t ws_size,
                              hipStream_t stream) {
    const float* x    = (const float*)d_in[0];
    const int*   ei   = (const int*)d_in[1];
    const int*   src  = ei;
    const int*   dst  = ei + N_EDGES;
    const int*   y    = (const int*)d_in[2];
    const float* w1_l = (const float*)d_in[3];
    const float* b1   = (const float*)d_in[4];
    const float* w1_r = (const float*)d_in[5];
    const float* w2_l = (const float*)d_in[6];
    const float* b2   = (const float*)d_in[7];
    const float* w2_r = (const float*)d_in[8];
    const float* ow1  = (const float*)d_in[9];
    const float* ob1  = (const float*)d_in[10];
    const float* ow2  = (const float*)d_in[11];
    const float* ob2  = (const float*)d_in[12];
    const float* ow3  = (const float*)d_in[13];
    const float* ob3  = (const float*)d_in[14];
    const float* ow4  = (const float*)d_in[15];
    const float* ob4  = (const float*)d_in[16];
    const float* rw1  = (const float*)d_in[17];
    const float* rb1  = (const float*)d_in[18];
    const float* rw2  = (const float*)d_in[19];
    const float* rb2  = (const float*)d_in[20];
    const float* rw3  = (const float*)d_in[21];
    const float* rb3  = (const float*)d_in[22];

    float* ws     = (float*)d_ws;
    int*   cnt_i  = (int*)(ws + CNTI_OFF);
    int*   starts = (int*)(ws + STARTS_OFF);
    int*   cursor = (int*)(ws + CURSOR_OFF);
    int*   srcb   = (int*)(ws + SRCB_OFF);
    short* prb    = (short*)(ws + PRB_OFF);
    short* h1b    = (short*)(ws + H1_OFF);
    short* plb    = (short*)(ws + PLB_OFF);
    float* out    = (float*)d_out;

    hipMemsetAsync(cnt_i, 0, N_NODES * sizeof(int), stream);

    k_histy <<<(N_EDGES + 255) / 256, 256, 0, stream>>>(dst, cnt_i, y, out);
    k_scan  <<<1, 1024, 0, stream>>>(cnt_i, starts, cursor);
    k_bucket<<<(N_EDGES + 255) / 256, 256, 0, stream>>>(src, dst, cursor, srcb);

    k_sage1g<<<NODE_TILES, 256, 0, stream>>>(x, srcb, starts, cnt_i, w1_l, b1, w1_r, h1b);
    k_sage2g<<<NODE_TILES, 256, 0, stream>>>(h1b, srcb, starts, cnt_i,
                                             w2_l, b2, w2_r, ow1, plb, prb);

    k_edge3<<<EBLOCKS, 256, 0, stream>>>(
        plb, prb, src, dst,
        ob1, ow2, ob2, ow3, ob3, ow4, ob4,
        rw1, rb1, rw2, rb2, rw3, rb3, out);
}

// Round 10
// 433.122 us; speedup vs baseline: 1.0260x; 1.0260x over previous
//
#include <hip/hip_runtime.h>
#include <hip/hip_bf16.h>

#define N_NODES 50000
#define N_EDGES 500000
#define N_REL   50
#define NTILES  ((N_EDGES + 63) / 64)   // 7813
#define EBLOCKS 1024
#define NODE_TILES ((N_NODES + 63) / 64)  // 782

// workspace layout (float-sized slots)
#define CNTI_OFF   0                          // int[50000]  (memset to 0)
#define STARTS_OFF (CNTI_OFF + N_NODES)
#define CURSOR_OFF (STARTS_OFF + N_NODES)
#define SRCB_OFF   (CURSOR_OFF + N_NODES)     // int[500000] src grouped by dst
#define PRB_OFF    (SRCB_OFF + N_EDGES)       // short[50000*128] (bf16)
#define H1_OFF     (PRB_OFF + N_NODES*32)     // short[50000*64]  (bf16)
#define PLB_OFF    (H1_OFF + N_NODES*32)      // short[50000*128] (bf16)
// end = PLB_OFF + N_NODES*32 = 8.65M floats = 34.6 MB

typedef short short8  __attribute__((ext_vector_type(8)));
typedef short short4v __attribute__((ext_vector_type(4)));
typedef float f32x4   __attribute__((ext_vector_type(4)));
typedef float f4      __attribute__((ext_vector_type(4)));

#define MFMA16(a,b,c) __builtin_amdgcn_mfma_f32_16x16x32_bf16((a),(b),(c),0,0,0)

__device__ __forceinline__ short f2bf(float x) {
    unsigned u = __float_as_uint(x);
    unsigned r = (u + 0x7fffu + ((u >> 16) & 1u)) >> 16;   // RNE
    return (short)r;
}
__device__ __forceinline__ float bf2f(short s) {
    return __uint_as_float(((unsigned)(unsigned short)s) << 16);
}

__device__ __forceinline__ short8 load_wfrag(const float* __restrict__ W, int row, int K, int k) {
    const f4* p = (const f4*)(W + (size_t)row * K + k);
    f4 a = p[0], b = p[1];
    short8 r;
    r[0] = f2bf(a[0]); r[1] = f2bf(a[1]); r[2] = f2bf(a[2]); r[3] = f2bf(a[3]);
    r[4] = f2bf(b[0]); r[5] = f2bf(b[1]); r[6] = f2bf(b[2]); r[7] = f2bf(b[7-7]); // placeholder fixed below
    r[4] = f2bf(b[0]); r[5] = f2bf(b[1]); r[6] = f2bf(b[2]); r[7] = f2bf(b[3]);
    return r;
}

// ---------------- CSR build ----------------

__global__ __launch_bounds__(256) void k_histy(
    const int* __restrict__ dst, int* __restrict__ cnt_i,
    const int* __restrict__ y, float* __restrict__ out)
{
    int e = blockIdx.x * blockDim.x + threadIdx.x;
    if (e < N_EDGES) {
        atomicAdd(&cnt_i[dst[e]], 1);
        out[(size_t)N_EDGES * N_REL + e] = (float)y[e];
    }
}

__global__ __launch_bounds__(1024) void k_scan(
    const int* __restrict__ cnt_i, int* __restrict__ starts, int* __restrict__ cursor)
{
    __shared__ int part[1024];
    const int i  = threadIdx.x;
    const int lo = i * 49;
    const int hi = min(N_NODES, lo + 49);
    int s = 0;
    for (int j = lo; j < hi; ++j) s += cnt_i[j];
    part[i] = s;
    __syncthreads();
    for (int d = 1; d < 1024; d <<= 1) {
        int v = (i >= d) ? part[i - d] : 0;
        __syncthreads();
        part[i] += v;
        __syncthreads();
    }
    int off = (i == 0) ? 0 : part[i - 1];
    for (int j = lo; j < hi; ++j) {
        starts[j] = off;
        cursor[j] = off;
        off += cnt_i[j];
    }
}

__global__ __launch_bounds__(256) void k_bucket(
    const int* __restrict__ src, const int* __restrict__ dst,
    int* __restrict__ cursor, int* __restrict__ srcb)
{
    int e = blockIdx.x * blockDim.x + threadIdx.x;
    if (e < N_EDGES) {
        int pos = atomicAdd(&cursor[dst[e]], 1);
        srcb[pos] = src[e];
    }
}

// ---------------- SAGE1 with fused in-edge gather ----------------
__global__ __launch_bounds__(256) void k_sage1g(
    const float* __restrict__ x, const int* __restrict__ srcb,
    const int* __restrict__ starts, const int* __restrict__ cnt_i,
    const float* __restrict__ w1_l, const float* __restrict__ b1,
    const float* __restrict__ w1_r, short* __restrict__ h1b)
{
    __shared__ short feat[64 * 40];

    const int t    = threadIdx.x;
    const int w    = t >> 6;
    const int lane = t & 63;
    const int lr   = lane & 15;
    const int lg   = lane >> 4;
    const int base = blockIdx.x * 64;

    short8 w1f;
    if (lg < 2) w1f = load_wfrag(w1_l, w * 16 + lr, 16, lg * 8);
    else        w1f = load_wfrag(w1_r, w * 16 + lr, 16, (lg - 2) * 8);

    {
        int e  = t >> 2, q = t & 3;
        int ng = base + e;
        short8 v = (short8)0;
        if (ng < N_NODES) {
            if (q < 2) {
                int st = starts[ng], c = cnt_i[ng];
                float acc[8] = {0, 0, 0, 0, 0, 0, 0, 0};
                for (int i = 0; i < c; ++i) {
                    const float* xp = x + (size_t)srcb[st + i] * 16 + q * 8;
                    f4 a = *(const f4*)xp;
                    f4 b = *(const f4*)(xp + 4);
#pragma unroll
                    for (int j = 0; j < 4; ++j) { acc[j] += a[j]; acc[4 + j] += b[j]; }
                }
                float inv = 1.0f / (float)(c > 0 ? c : 1);
#pragma unroll
                for (int j = 0; j < 8; ++j) v[j] = f2bf(acc[j] * inv);
            } else {
                f4 a = *(const f4*)(x + (size_t)ng * 16 + (q - 2) * 8);
                f4 b = *(const f4*)(x + (size_t)ng * 16 + (q - 2) * 8 + 4);
#pragma unroll
                for (int j = 0; j < 4; ++j) { v[j] = f2bf(a[j]); v[4 + j] = f2bf(b[j]); }
            }
        }
        *(short8*)&feat[e * 40 + q * 8] = v;
    }
    __syncthreads();

    f32x4 acc[4];
    f4 bia = *(const f4*)&b1[w * 16 + lg * 4];
#pragma unroll
    for (int nt = 0; nt < 4; ++nt) {
        acc[nt][0] = bia[0]; acc[nt][1] = bia[1]; acc[nt][2] = bia[2]; acc[nt][3] = bia[3];
    }
#pragma unroll
    for (int nt = 0; nt < 4; ++nt) {
        int e = nt * 16 + lr;
        short8 bf = *(const short8*)&feat[e * 40 + lg * 8];
        acc[nt] = MFMA16(w1f, bf, acc[nt]);
    }
#pragma unroll
    for (int nt = 0; nt < 4; ++nt) {
        int ng = base + nt * 16 + lr;
        if (ng < N_NODES) {
            short4v o;
#pragma unroll
            for (int r = 0; r < 4; ++r) { float v = acc[nt][r]; o[r] = f2bf(v > 0.0f ? v : 0.0f); }
            *(short4v*)&h1b[(size_t)ng * 64 + w * 16 + lg * 4] = o;
        }
    }
}

// ---------------- SAGE2 + proj, with 4-way-parallel fused gather ------------
__global__ __launch_bounds__(256) void k_sage2g(
    const short* __restrict__ h1b, const int* __restrict__ srcb,
    const int* __restrict__ starts, const int* __restrict__ cnt_i,
    const float* __restrict__ w2_l, const float* __restrict__ b2,
    const float* __restrict__ w2_r, const float* __restrict__ ow1,
    short* __restrict__ plb, short* __restrict__ prb)
{
    __shared__ short feat[64 * 128];
    __shared__ short feat2[64 * 128];   // phase-A output; pscr scratch before that

    const int t    = threadIdx.x;
    const int w    = t >> 6;
    const int lane = t & 63;
    const int lr   = lane & 15;
    const int lg   = lane >> 4;
    const int base = blockIdx.x * 64;

    short8 wf[2][4];
#pragma unroll
    for (int mt = 0; mt < 2; ++mt)
#pragma unroll
        for (int kt = 0; kt < 4; ++kt) {
            int row = w * 32 + mt * 16 + lr;
            int k   = kt * 32 + lg * 8;
            wf[mt][kt] = (k < 64) ? load_wfrag(w2_r, row, 64, k)
                                  : load_wfrag(w2_l, row, 64, k - 64);
        }

    {
        int e = t >> 2, q = t & 3;
        int ng = base + e;
        int half = q & 1;          // feat half (32 feats)
        int par  = q >> 1;         // edge parity
        float acc[32];
#pragma unroll
        for (int j = 0; j < 32; ++j) acc[j] = 0.0f;
        int c = 0;
        if (ng < N_NODES) {
            int st = starts[ng];
            c = cnt_i[ng];
            for (int i = par; i < c; i += 2) {
                const short8* hp = (const short8*)(h1b + (size_t)srcb[st + i] * 64 + half * 32);
                short8 a0 = hp[0], a1 = hp[1], a2 = hp[2], a3 = hp[3];
#pragma unroll
                for (int j = 0; j < 8; ++j) {
                    acc[j]      += bf2f(a0[j]);
                    acc[8 + j]  += bf2f(a1[j]);
                    acc[16 + j] += bf2f(a2[j]);
                    acc[24 + j] += bf2f(a3[j]);
                }
            }
        }
        float* pscr = (float*)feat2;   // [64 nodes][64 feats]
        if (q >= 2) {
#pragma unroll
            for (int j = 0; j < 32; ++j) pscr[e * 64 + half * 32 + j] = acc[j];
        }
        __builtin_amdgcn_wave_barrier();   // node's 4 threads are wave-adjacent
        if (q < 2) {
#pragma unroll
            for (int j = 0; j < 32; ++j) acc[j] += pscr[e * 64 + q * 32 + j];
            float inv = 1.0f / (float)(c > 0 ? c : 1);
#pragma unroll
            for (int jj = 0; jj < 4; ++jj) {
                short8 v;
#pragma unroll
                for (int j = 0; j < 8; ++j) v[j] = f2bf(acc[jj * 8 + j] * inv);
                int scol = (q * 32 + 64 + jj * 8) ^ ((e & 7) << 3);
                *(short8*)&feat[e * 128 + scol] = v;
            }
        } else {
            const short* hp = (ng < N_NODES) ? (h1b + (size_t)ng * 64 + (q - 2) * 32) : nullptr;
#pragma unroll
            for (int j = 0; j < 4; ++j) {
                short8 v = hp ? *(const short8*)(hp + j * 8) : (short8)0;
                int scol = ((q - 2) * 32 + j * 8) ^ ((e & 7) << 3);
                *(short8*)&feat[e * 128 + scol] = v;
            }
        }
    }
    __syncthreads();   // feat ready; pscr (feat2) dead

    // phase A: h2 tile (bf16, swizzled, LDS only)
    {
        f32x4 acc[2][4];
#pragma unroll
        for (int mt = 0; mt < 2; ++mt) {
            f4 bia = *(const f4*)&b2[w * 32 + mt * 16 + lg * 4];
#pragma unroll
            for (int nt = 0; nt < 4; ++nt) {
                acc[mt][nt][0] = bia[0]; acc[mt][nt][1] = bia[1];
                acc[mt][nt][2] = bia[2]; acc[mt][nt][3] = bia[3];
            }
        }
#pragma unroll
        for (int kt = 0; kt < 4; ++kt) {
            short8 bf[4];
#pragma unroll
            for (int nt = 0; nt < 4; ++nt) {
                int e = nt * 16 + lr;
                int scol = (kt * 32 + lg * 8) ^ ((e & 7) << 3);
                bf[nt] = *(const short8*)&feat[e * 128 + scol];
            }
#pragma unroll
            for (int mt = 0; mt < 2; ++mt)
#pragma unroll
                for (int nt = 0; nt < 4; ++nt)
                    acc[mt][nt] = MFMA16(wf[mt][kt], bf[nt], acc[mt][nt]);
        }
#pragma unroll
        for (int mt = 0; mt < 2; ++mt)
#pragma unroll
            for (int nt = 0; nt < 4; ++nt) {
                int e  = nt * 16 + lr;
                int n0 = w * 32 + mt * 16 + lg * 4;
                short4v s;
#pragma unroll
                for (int r = 0; r < 4; ++r) {
                    float v = acc[mt][nt][r];
                    s[r] = f2bf(v > 0.0f ? v : 0.0f);
                }
                *(short4v*)&feat2[e * 128 + (n0 ^ ((e & 7) << 3))] = s;
            }
    }
    __syncthreads();

    // phase B: PL / PR projections
    short8 wfL[2][4], wfR[2][4];
#pragma unroll
    for (int mt = 0; mt < 2; ++mt)
#pragma unroll
        for (int kt = 0; kt < 4; ++kt) {
            int row = w * 32 + mt * 16 + lr;
            int k   = kt * 32 + lg * 8;
            wfL[mt][kt] = load_wfrag(ow1, row, 256, k);
            wfR[mt][kt] = load_wfrag(ow1, row, 256, 128 + k);
        }
    f32x4 aL[2][4], aR[2][4];
#pragma unroll
    for (int mt = 0; mt < 2; ++mt)
#pragma unroll
        for (int nt = 0; nt < 4; ++nt) { aL[mt][nt] = (f32x4)0.0f; aR[mt][nt] = (f32x4)0.0f; }
#pragma unroll
    for (int kt = 0; kt < 4; ++kt) {
        short8 bf[4];
#pragma unroll
        for (int nt = 0; nt < 4; ++nt) {
            int e = nt * 16 + lr;
            int scol = (kt * 32 + lg * 8) ^ ((e & 7) << 3);
            bf[nt] = *(const short8*)&feat2[e * 128 + scol];
        }
#pragma unroll
        for (int mt = 0; mt < 2; ++mt)
#pragma unroll
            for (int nt = 0; nt < 4; ++nt) {
                aL[mt][nt] = MFMA16(wfL[mt][kt], bf[nt], aL[mt][nt]);
                aR[mt][nt] = MFMA16(wfR[mt][kt], bf[nt], aR[mt][nt]);
            }
    }
#pragma unroll
    for (int mt = 0; mt < 2; ++mt)
#pragma unroll
        for (int nt = 0; nt < 4; ++nt) {
            int ng = base + nt * 16 + lr;
            if (ng < N_NODES) {
                int n0 = w * 32 + mt * 16 + lg * 4;
                short4v oL, oR;
#pragma unroll
                for (int r = 0; r < 4; ++r) { oL[r] = f2bf(aL[mt][nt][r]); oR[r] = f2bf(aR[mt][nt][r]); }
                *(short4v*)&plb[(size_t)ng * 128 + n0] = oL;
                *(short4v*)&prb[(size_t)ng * 128 + n0] = oR;
            }
        }
}

// ---------------- edge MLP v4: prefetch, block-wide aligned output ----------
__global__ __launch_bounds__(256, 4) void k_edge3(
    const short* __restrict__ plb, const short* __restrict__ prb,
    const int* __restrict__ src, const int* __restrict__ dst,
    const float* __restrict__ ob1,
    const float* __restrict__ ow2, const float* __restrict__ ob2,
    const float* __restrict__ ow3, const float* __restrict__ ob3,
    const float* __restrict__ ow4, const float* __restrict__ ob4,
    const float* __restrict__ rw1, const float* __restrict__ rb1,
    const float* __restrict__ rw2, const float* __restrict__ rb2,
    const float* __restrict__ rw3, const float* __restrict__ rb3,
    float* __restrict__ out)
{
    __shared__ short a1s[64 * 128];    // 16KB; tail T aliases
    __shared__ short actB[64 * 96];    // act2 | act3
    __shared__ float sw[662];

    short* act2  = actB;
    short* act3  = actB + 64 * 64;
    float* tailf = (float*)a1s;        // T region: wave w uses [w*512, w*512+512)

    const int t    = threadIdx.x;
    const int w    = t >> 6;
    const int lane = t & 63;
    const int lr   = lane & 15;
    const int lg   = lane >> 4;

    if (t < 128) sw[t]       = ob1[t];
    if (t < 64)  sw[128 + t] = ob2[t];
    if (t < 32)  sw[192 + t] = ob3[t];
    if (t < 16)  sw[224 + t] = ob4[t];
    if (t < 8)   sw[240 + t] = rb1[t];
    if (t < 4)   sw[248 + t] = rb2[t];
    if (t < 50)  sw[252 + t] = rb3[t];
    if (t < 128) sw[302 + t] = rw1[t];
    if (t < 32)  sw[430 + t] = rw2[t];
    if (t < 200) sw[462 + t] = rw3[t];

    short8 w2f[4];
#pragma unroll
    for (int kt = 0; kt < 4; ++kt)
        w2f[kt] = load_wfrag(ow2, w * 16 + lr, 128, kt * 32 + lg * 8);

    short8 w3f[2][2];
#pragma unroll
    for (int mt = 0; mt < 2; ++mt)
#pragma unroll
        for (int kt = 0; kt < 2; ++kt)
            w3f[mt][kt] = load_wfrag(ow3, mt * 16 + lr, 64, kt * 32 + lg * 8);

    short8 w4f = load_wfrag(ow4, lr, 32, lg * 8);

    __syncthreads();   // sw ready

    const int e = t >> 2, p = t & 3;
    short8 vl0, vl1, vl2, vl3, vr0, vr1, vr2, vr3;

#define LOADTILE(TI)                                                        \
    {                                                                       \
        int eg  = (TI) * 64 + e;                                            \
        int egc = eg < N_EDGES ? eg : N_EDGES - 1;                          \
        int sn = src[egc], dn = dst[egc];                                   \
        const short8* plp = (const short8*)(plb + (size_t)sn * 128 + p * 32); \
        const short8* prp = (const short8*)(prb + (size_t)dn * 128 + p * 32); \
        vl0 = plp[0]; vl1 = plp[1]; vl2 = plp[2]; vl3 = plp[3];             \
        vr0 = prp[0]; vr1 = prp[1]; vr2 = prp[2]; vr3 = prp[3];             \
    }

    LOADTILE(blockIdx.x)

    for (int tile = blockIdx.x; tile < NTILES; tile += EBLOCKS) {
        const int base = tile * 64;

        // ---- stage a1 = relu(PL[src] + PR[dst] + ob1), bf16, swizzled ----
        {
            short8 VL[4] = {vl0, vl1, vl2, vl3};
            short8 VR[4] = {vr0, vr1, vr2, vr3};
#pragma unroll
            for (int j = 0; j < 4; ++j) {
                short8 s;
#pragma unroll
                for (int i = 0; i < 8; ++i) {
                    float v = bf2f(VL[j][i]) + bf2f(VR[j][i]) + sw[p * 32 + j * 8 + i];
                    s[i] = f2bf(v > 0.0f ? v : 0.0f);
                }
                int scol = (p * 32 + j * 8) ^ ((e & 7) << 3);
                *(short8*)&a1s[e * 128 + scol] = s;
            }
        }
        __syncthreads();

        // ---- prefetch next tile (flies during L2 + tail) ----
        if (tile + EBLOCKS < NTILES) LOADTILE(tile + EBLOCKS)

        // ---- L2: 128 -> 64, relu ----
        {
            f32x4 acc[4];
            f32x4 bia;
#pragma unroll
            for (int r = 0; r < 4; ++r) bia[r] = sw[128 + w * 16 + lg * 4 + r];
#pragma unroll
            for (int nt = 0; nt < 4; ++nt) acc[nt] = bia;
#pragma unroll
            for (int kt = 0; kt < 4; ++kt) {
#pragma unroll
                for (int nt = 0; nt < 4; ++nt) {
                    int en = nt * 16 + lr;
                    int scol = (kt * 32 + lg * 8) ^ ((en & 7) << 3);
                    short8 bf = *(const short8*)&a1s[en * 128 + scol];
                    acc[nt] = MFMA16(w2f[kt], bf, acc[nt]);
                }
            }
#pragma unroll
            for (int nt = 0; nt < 4; ++nt) {
                int en = nt * 16 + lr;
                int n0 = w * 16 + lg * 4;
                short4v s;
#pragma unroll
                for (int r = 0; r < 4; ++r) {
                    float v = acc[nt][r];
                    s[r] = f2bf(v > 0.0f ? v : 0.0f);
                }
                *(short4v*)&act2[en * 64 + (n0 ^ ((en & 7) << 3))] = s;
            }
        }
        __syncthreads();   // act2 ready; a1s dead -> tail T may alias

        // ---- wave-local tail: L3, L4, rf1, rf2 ----
        {
            const int e3 = w * 16 + lr;
            float* T = tailf + w * 512;

            f32x4 acc[2];
#pragma unroll
            for (int mt = 0; mt < 2; ++mt)
#pragma unroll
                for (int r = 0; r < 4; ++r) acc[mt][r] = sw[192 + mt * 16 + lg * 4 + r];
#pragma unroll
            for (int kt = 0; kt < 2; ++kt) {
                int scol = (kt * 32 + lg * 8) ^ ((e3 & 7) << 3);
                short8 bf = *(const short8*)&act2[e3 * 64 + scol];
#pragma unroll
                for (int mt = 0; mt < 2; ++mt)
                    acc[mt] = MFMA16(w3f[mt][kt], bf, acc[mt]);
            }
#pragma unroll
            for (int mt = 0; mt < 2; ++mt) {
                short4v s;
#pragma unroll
                for (int r = 0; r < 4; ++r) {
                    float v = acc[mt][r];
                    s[r] = f2bf(v > 0.0f ? v : 0.0f);
                }
                *(short4v*)&act3[e3 * 32 + mt * 16 + lg * 4] = s;
            }
            __builtin_amdgcn_wave_barrier();

            {
                short8 bf = *(const short8*)&act3[e3 * 32 + lg * 8];
                f32x4 a4;
#pragma unroll
                for (int r = 0; r < 4; ++r) a4[r] = sw[224 + lg * 4 + r];
                a4 = MFMA16(w4f, bf, a4);
#pragma unroll
                for (int r = 0; r < 4; ++r) T[lr * 17 + lg * 4 + r] = a4[r];
            }
            __builtin_amdgcn_wave_barrier();

            {
                float af[16];
#pragma unroll
                for (int f = 0; f < 16; ++f) af[f] = T[lr * 17 + f];
#pragma unroll
                for (int oo = 0; oo < 2; ++oo) {
                    int o = lg * 2 + oo;
                    float v = sw[240 + o];
#pragma unroll
                    for (int f = 0; f < 16; ++f) v += af[f] * sw[302 + o * 16 + f];
                    T[272 + lr * 9 + o] = v > 0.0f ? v : 0.0f;
                }
            }
            __builtin_amdgcn_wave_barrier();

            {
                float v = sw[248 + lg];
#pragma unroll
                for (int f = 0; f < 8; ++f) v += T[272 + lr * 9 + f] * sw[430 + lg * 8 + f];
                T[416 + lr * 5 + lg] = v > 0.0f ? v : 0.0f;
            }
        }
        __syncthreads();   // all waves' T ready for block-wide rf3

        // ---- rf3: 4 -> 50, BLOCK-WIDE contiguous write (12800 B, 128B-aligned) ----
        {
            size_t obase = (size_t)base * N_REL;
#pragma unroll
            for (int k2 = 0; k2 < 13; ++k2) {
                int idx = k2 * 256 + t;
                if (idx < 64 * N_REL) {
                    int ee = idx / N_REL;          // tile-local edge 0..63
                    int o  = idx - ee * N_REL;
                    if (base + ee < N_EDGES) {
                        const float* Te = tailf + (ee >> 4) * 512 + 416 + (ee & 15) * 5;
                        float v = sw[252 + o];
#pragma unroll
                        for (int f = 0; f < 4; ++f) v += Te[f] * sw[462 + o * 4 + f];
                        out[obase + idx] = v;
                    }
                }
            }
        }
        __syncthreads();   // protect T / act buffers before next staging
    }
#undef LOADTILE
}

extern "C" void kernel_launch(void* const* d_in, const int* in_sizes, int n_in,
                              void* d_out, int out_size, void* d_ws, size_t ws_size,
                              hipStream_t stream) {
    const float* x    = (const float*)d_in[0];
    const int*   ei   = (const int*)d_in[1];
    const int*   src  = ei;
    const int*   dst  = ei + N_EDGES;
    const int*   y    = (const int*)d_in[2];
    const float* w1_l = (const float*)d_in[3];
    const float* b1   = (const float*)d_in[4];
    const float* w1_r = (const float*)d_in[5];
    const float* w2_l = (const float*)d_in[6];
    const float* b2   = (const float*)d_in[7];
    const float* w2_r = (const float*)d_in[8];
    const float* ow1  = (const float*)d_in[9];
    const float* ob1  = (const float*)d_in[10];
    const float* ow2  = (const float*)d_in[11];
    const float* ob2  = (const float*)d_in[12];
    const float* ow3  = (const float*)d_in[13];
    const float* ob3  = (const float*)d_in[14];
    const float* ow4  = (const float*)d_in[15];
    const float* ob4  = (const float*)d_in[16];
    const float* rw1  = (const float*)d_in[17];
    const float* rb1  = (const float*)d_in[18];
    const float* rw2  = (const float*)d_in[19];
    const float* rb2  = (const float*)d_in[20];
    const float* rw3  = (const float*)d_in[21];
    const float* rb3  = (const float*)d_in[22];

    float* ws     = (float*)d_ws;
    int*   cnt_i  = (int*)(ws + CNTI_OFF);
    int*   starts = (int*)(ws + STARTS_OFF);
    int*   cursor = (int*)(ws + CURSOR_OFF);
    int*   srcb   = (int*)(ws + SRCB_OFF);
    short* prb    = (short*)(ws + PRB_OFF);
    short* h1b    = (short*)(ws + H1_OFF);
    short* plb    = (short*)(ws + PLB_OFF);
    float* out    = (float*)d_out;

    hipMemsetAsync(cnt_i, 0, N_NODES * sizeof(int), stream);

    k_histy <<<(N_EDGES + 255) / 256, 256, 0, stream>>>(dst, cnt_i, y, out);
    k_scan  <<<1, 1024, 0, stream>>>(cnt_i, starts, cursor);
    k_bucket<<<(N_EDGES + 255) / 256, 256, 0, stream>>>(src, dst, cursor, srcb);

    k_sage1g<<<NODE_TILES, 256, 0, stream>>>(x, srcb, starts, cnt_i, w1_l, b1, w1_r, h1b);
    k_sage2g<<<NODE_TILES, 256, 0, stream>>>(h1b, srcb, starts, cnt_i,
                                             w2_l, b2, w2_r, ow1, plb, prb);

    k_edge3<<<EBLOCKS, 256, 0, stream>>>(
        plb, prb, src, dst,
        ob1, ow2, ob2, ow3, ob3, ow4, ob4,
        rw1, rb1, rw2, rb2, rw3, rb3, out);
}

// Round 11
// 404.585 us; speedup vs baseline: 1.0984x; 1.0705x over previous
//
#include <hip/hip_runtime.h>
#include <hip/hip_bf16.h>

#define N_NODES 50000
#define N_EDGES 500000
#define N_REL   50
#define NTILES  ((N_EDGES + 63) / 64)   // 7813
#define EBLOCKS 1024
#define NODE_TILES ((N_NODES + 63) / 64)  // 782

// workspace layout (float-sized slots)
#define CNTI_OFF   0                          // int[50000]  (memset to 0)
#define STARTS_OFF (CNTI_OFF + N_NODES)
#define CURSOR_OFF (STARTS_OFF + N_NODES)
#define SRCB_OFF   (CURSOR_OFF + N_NODES)     // int[500000] src grouped by dst
#define PRB_OFF    (SRCB_OFF + N_EDGES)       // short[50000*128] (bf16)
#define H1_OFF     (PRB_OFF + N_NODES*32)     // short[50000*64]  (bf16)
#define PLB_OFF    (H1_OFF + N_NODES*32)      // short[50000*128] (bf16)
// end = PLB_OFF + N_NODES*32 = 8.65M floats = 34.6 MB

typedef short short8  __attribute__((ext_vector_type(8)));
typedef short short4v __attribute__((ext_vector_type(4)));
typedef float f32x4   __attribute__((ext_vector_type(4)));
typedef float f4      __attribute__((ext_vector_type(4)));

#define MFMA16(a,b,c) __builtin_amdgcn_mfma_f32_16x16x32_bf16((a),(b),(c),0,0,0)

__device__ __forceinline__ short f2bf(float x) {
    unsigned u = __float_as_uint(x);
    unsigned r = (u + 0x7fffu + ((u >> 16) & 1u)) >> 16;   // RNE
    return (short)r;
}
__device__ __forceinline__ float bf2f(short s) {
    return __uint_as_float(((unsigned)(unsigned short)s) << 16);
}

__device__ __forceinline__ short8 load_wfrag(const float* __restrict__ W, int row, int K, int k) {
    const f4* p = (const f4*)(W + (size_t)row * K + k);
    f4 a = p[0], b = p[1];
    short8 r;
    r[0] = f2bf(a[0]); r[1] = f2bf(a[1]); r[2] = f2bf(a[2]); r[3] = f2bf(a[3]);
    r[4] = f2bf(b[0]); r[5] = f2bf(b[1]); r[6] = f2bf(b[2]); r[7] = f2bf(b[3]);
    return r;
}

// ---------------- CSR build ----------------

__global__ __launch_bounds__(256) void k_histy(
    const int* __restrict__ dst, int* __restrict__ cnt_i,
    const int* __restrict__ y, float* __restrict__ out)
{
    int e = blockIdx.x * blockDim.x + threadIdx.x;
    if (e < N_EDGES) {
        atomicAdd(&cnt_i[dst[e]], 1);
        out[(size_t)N_EDGES * N_REL + e] = (float)y[e];
    }
}

__global__ __launch_bounds__(1024) void k_scan(
    const int* __restrict__ cnt_i, int* __restrict__ starts, int* __restrict__ cursor)
{
    __shared__ int part[1024];
    const int i  = threadIdx.x;
    const int lo = i * 49;
    const int hi = min(N_NODES, lo + 49);
    int s = 0;
    for (int j = lo; j < hi; ++j) s += cnt_i[j];
    part[i] = s;
    __syncthreads();
    for (int d = 1; d < 1024; d <<= 1) {
        int v = (i >= d) ? part[i - d] : 0;
        __syncthreads();
        part[i] += v;
        __syncthreads();
    }
    int off = (i == 0) ? 0 : part[i - 1];
    for (int j = lo; j < hi; ++j) {
        starts[j] = off;
        cursor[j] = off;
        off += cnt_i[j];
    }
}

__global__ __launch_bounds__(256) void k_bucket(
    const int* __restrict__ src, const int* __restrict__ dst,
    int* __restrict__ cursor, int* __restrict__ srcb)
{
    int e = blockIdx.x * blockDim.x + threadIdx.x;
    if (e < N_EDGES) {
        int pos = atomicAdd(&cursor[dst[e]], 1);
        srcb[pos] = src[e];
    }
}

// ---------------- SAGE1 with fused in-edge gather ----------------
__global__ __launch_bounds__(256) void k_sage1g(
    const float* __restrict__ x, const int* __restrict__ srcb,
    const int* __restrict__ starts, const int* __restrict__ cnt_i,
    const float* __restrict__ w1_l, const float* __restrict__ b1,
    const float* __restrict__ w1_r, short* __restrict__ h1b)
{
    __shared__ short feat[64 * 40];

    const int t    = threadIdx.x;
    const int w    = t >> 6;
    const int lane = t & 63;
    const int lr   = lane & 15;
    const int lg   = lane >> 4;
    const int base = blockIdx.x * 64;

    short8 w1f;
    if (lg < 2) w1f = load_wfrag(w1_l, w * 16 + lr, 16, lg * 8);
    else        w1f = load_wfrag(w1_r, w * 16 + lr, 16, (lg - 2) * 8);

    {
        int e  = t >> 2, q = t & 3;
        int ng = base + e;
        short8 v = (short8)0;
        if (ng < N_NODES) {
            if (q < 2) {
                int st = starts[ng], c = cnt_i[ng];
                float acc[8] = {0, 0, 0, 0, 0, 0, 0, 0};
                for (int i = 0; i < c; ++i) {
                    const float* xp = x + (size_t)srcb[st + i] * 16 + q * 8;
                    f4 a = *(const f4*)xp;
                    f4 b = *(const f4*)(xp + 4);
#pragma unroll
                    for (int j = 0; j < 4; ++j) { acc[j] += a[j]; acc[4 + j] += b[j]; }
                }
                float inv = 1.0f / (float)(c > 0 ? c : 1);
#pragma unroll
                for (int j = 0; j < 8; ++j) v[j] = f2bf(acc[j] * inv);
            } else {
                f4 a = *(const f4*)(x + (size_t)ng * 16 + (q - 2) * 8);
                f4 b = *(const f4*)(x + (size_t)ng * 16 + (q - 2) * 8 + 4);
#pragma unroll
                for (int j = 0; j < 4; ++j) { v[j] = f2bf(a[j]); v[4 + j] = f2bf(b[j]); }
            }
        }
        *(short8*)&feat[e * 40 + q * 8] = v;
    }
    __syncthreads();

    f32x4 acc[4];
    f4 bia = *(const f4*)&b1[w * 16 + lg * 4];
#pragma unroll
    for (int nt = 0; nt < 4; ++nt) {
        acc[nt][0] = bia[0]; acc[nt][1] = bia[1]; acc[nt][2] = bia[2]; acc[nt][3] = bia[3];
    }
#pragma unroll
    for (int nt = 0; nt < 4; ++nt) {
        int e = nt * 16 + lr;
        short8 bf = *(const short8*)&feat[e * 40 + lg * 8];
        acc[nt] = MFMA16(w1f, bf, acc[nt]);
    }
#pragma unroll
    for (int nt = 0; nt < 4; ++nt) {
        int ng = base + nt * 16 + lr;
        if (ng < N_NODES) {
            short4v o;
#pragma unroll
            for (int r = 0; r < 4; ++r) { float v = acc[nt][r]; o[r] = f2bf(v > 0.0f ? v : 0.0f); }
            *(short4v*)&h1b[(size_t)ng * 64 + w * 16 + lg * 4] = o;
        }
    }
}

// ---------------- SAGE2 + proj, with 4-way-parallel fused gather ------------
__global__ __launch_bounds__(256) void k_sage2g(
    const short* __restrict__ h1b, const int* __restrict__ srcb,
    const int* __restrict__ starts, const int* __restrict__ cnt_i,
    const float* __restrict__ w2_l, const float* __restrict__ b2,
    const float* __restrict__ w2_r, const float* __restrict__ ow1,
    short* __restrict__ plb, short* __restrict__ prb)
{
    __shared__ short feat[64 * 128];
    __shared__ short feat2[64 * 128];   // phase-A output; pscr scratch before that

    const int t    = threadIdx.x;
    const int w    = t >> 6;
    const int lane = t & 63;
    const int lr   = lane & 15;
    const int lg   = lane >> 4;
    const int base = blockIdx.x * 64;

    short8 wf[2][4];
#pragma unroll
    for (int mt = 0; mt < 2; ++mt)
#pragma unroll
        for (int kt = 0; kt < 4; ++kt) {
            int row = w * 32 + mt * 16 + lr;
            int k   = kt * 32 + lg * 8;
            wf[mt][kt] = (k < 64) ? load_wfrag(w2_r, row, 64, k)
                                  : load_wfrag(w2_l, row, 64, k - 64);
        }

    {
        int e = t >> 2, q = t & 3;
        int ng = base + e;
        int half = q & 1;          // feat half (32 feats)
        int par  = q >> 1;         // edge parity
        float acc[32];
#pragma unroll
        for (int j = 0; j < 32; ++j) acc[j] = 0.0f;
        int c = 0;
        if (ng < N_NODES) {
            int st = starts[ng];
            c = cnt_i[ng];
            for (int i = par; i < c; i += 2) {
                const short8* hp = (const short8*)(h1b + (size_t)srcb[st + i] * 64 + half * 32);
                short8 a0 = hp[0], a1 = hp[1], a2 = hp[2], a3 = hp[3];
#pragma unroll
                for (int j = 0; j < 8; ++j) {
                    acc[j]      += bf2f(a0[j]);
                    acc[8 + j]  += bf2f(a1[j]);
                    acc[16 + j] += bf2f(a2[j]);
                    acc[24 + j] += bf2f(a3[j]);
                }
            }
        }
        float* pscr = (float*)feat2;   // [64 nodes][64 feats]
        if (q >= 2) {
#pragma unroll
            for (int j = 0; j < 32; ++j) pscr[e * 64 + half * 32 + j] = acc[j];
        }
        __builtin_amdgcn_wave_barrier();   // node's 4 threads are wave-adjacent
        if (q < 2) {
#pragma unroll
            for (int j = 0; j < 32; ++j) acc[j] += pscr[e * 64 + q * 32 + j];
            float inv = 1.0f / (float)(c > 0 ? c : 1);
#pragma unroll
            for (int jj = 0; jj < 4; ++jj) {
                short8 v;
#pragma unroll
                for (int j = 0; j < 8; ++j) v[j] = f2bf(acc[jj * 8 + j] * inv);
                int scol = (q * 32 + 64 + jj * 8) ^ ((e & 7) << 3);
                *(short8*)&feat[e * 128 + scol] = v;
            }
        } else {
            const short* hp = (ng < N_NODES) ? (h1b + (size_t)ng * 64 + (q - 2) * 32) : nullptr;
#pragma unroll
            for (int j = 0; j < 4; ++j) {
                short8 v = hp ? *(const short8*)(hp + j * 8) : (short8)0;
                int scol = ((q - 2) * 32 + j * 8) ^ ((e & 7) << 3);
                *(short8*)&feat[e * 128 + scol] = v;
            }
        }
    }
    __syncthreads();   // feat ready; pscr (feat2) dead

    // phase A: h2 tile (bf16, swizzled, LDS only)
    {
        f32x4 acc[2][4];
#pragma unroll
        for (int mt = 0; mt < 2; ++mt) {
            f4 bia = *(const f4*)&b2[w * 32 + mt * 16 + lg * 4];
#pragma unroll
            for (int nt = 0; nt < 4; ++nt) {
                acc[mt][nt][0] = bia[0]; acc[mt][nt][1] = bia[1];
                acc[mt][nt][2] = bia[2]; acc[mt][nt][3] = bia[3];
            }
        }
#pragma unroll
        for (int kt = 0; kt < 4; ++kt) {
            short8 bf[4];
#pragma unroll
            for (int nt = 0; nt < 4; ++nt) {
                int e = nt * 16 + lr;
                int scol = (kt * 32 + lg * 8) ^ ((e & 7) << 3);
                bf[nt] = *(const short8*)&feat[e * 128 + scol];
            }
#pragma unroll
            for (int mt = 0; mt < 2; ++mt)
#pragma unroll
                for (int nt = 0; nt < 4; ++nt)
                    acc[mt][nt] = MFMA16(wf[mt][kt], bf[nt], acc[mt][nt]);
        }
#pragma unroll
        for (int mt = 0; mt < 2; ++mt)
#pragma unroll
            for (int nt = 0; nt < 4; ++nt) {
                int e  = nt * 16 + lr;
                int n0 = w * 32 + mt * 16 + lg * 4;
                short4v s;
#pragma unroll
                for (int r = 0; r < 4; ++r) {
                    float v = acc[mt][nt][r];
                    s[r] = f2bf(v > 0.0f ? v : 0.0f);
                }
                *(short4v*)&feat2[e * 128 + (n0 ^ ((e & 7) << 3))] = s;
            }
    }
    __syncthreads();

    // phase B: PL / PR projections
    short8 wfL[2][4], wfR[2][4];
#pragma unroll
    for (int mt = 0; mt < 2; ++mt)
#pragma unroll
        for (int kt = 0; kt < 4; ++kt) {
            int row = w * 32 + mt * 16 + lr;
            int k   = kt * 32 + lg * 8;
            wfL[mt][kt] = load_wfrag(ow1, row, 256, k);
            wfR[mt][kt] = load_wfrag(ow1, row, 256, 128 + k);
        }
    f32x4 aL[2][4], aR[2][4];
#pragma unroll
    for (int mt = 0; mt < 2; ++mt)
#pragma unroll
        for (int nt = 0; nt < 4; ++nt) { aL[mt][nt] = (f32x4)0.0f; aR[mt][nt] = (f32x4)0.0f; }
#pragma unroll
    for (int kt = 0; kt < 4; ++kt) {
        short8 bf[4];
#pragma unroll
        for (int nt = 0; nt < 4; ++nt) {
            int e = nt * 16 + lr;
            int scol = (kt * 32 + lg * 8) ^ ((e & 7) << 3);
            bf[nt] = *(const short8*)&feat2[e * 128 + scol];
        }
#pragma unroll
        for (int mt = 0; mt < 2; ++mt)
#pragma unroll
            for (int nt = 0; nt < 4; ++nt) {
                aL[mt][nt] = MFMA16(wfL[mt][kt], bf[nt], aL[mt][nt]);
                aR[mt][nt] = MFMA16(wfR[mt][kt], bf[nt], aR[mt][nt]);
            }
    }
#pragma unroll
    for (int mt = 0; mt < 2; ++mt)
#pragma unroll
        for (int nt = 0; nt < 4; ++nt) {
            int ng = base + nt * 16 + lr;
            if (ng < N_NODES) {
                int n0 = w * 32 + mt * 16 + lg * 4;
                short4v oL, oR;
#pragma unroll
                for (int r = 0; r < 4; ++r) { oL[r] = f2bf(aL[mt][nt][r]); oR[r] = f2bf(aR[mt][nt][r]); }
                *(short4v*)&plb[(size_t)ng * 128 + n0] = oL;
                *(short4v*)&prb[(size_t)ng * 128 + n0] = oR;
            }
        }
}

// ---------------- edge MLP v3 (R7 config): prefetch, per-wave tail + rf3 ----
__global__ __launch_bounds__(256, 4) void k_edge3(
    const short* __restrict__ plb, const short* __restrict__ prb,
    const int* __restrict__ src, const int* __restrict__ dst,
    const float* __restrict__ ob1,
    const float* __restrict__ ow2, const float* __restrict__ ob2,
    const float* __restrict__ ow3, const float* __restrict__ ob3,
    const float* __restrict__ ow4, const float* __restrict__ ob4,
    const float* __restrict__ rw1, const float* __restrict__ rb1,
    const float* __restrict__ rw2, const float* __restrict__ rb2,
    const float* __restrict__ rw3, const float* __restrict__ rb3,
    float* __restrict__ out)
{
    __shared__ short a1s[64 * 128];    // 16KB; tail T aliases
    __shared__ short actB[64 * 96];    // act2 | act3
    __shared__ float sw[662];

    short* act2  = actB;
    short* act3  = actB + 64 * 64;
    float* tailf = (float*)a1s;        // T region: wave w uses [w*512, w*512+512)

    const int t    = threadIdx.x;
    const int w    = t >> 6;
    const int lane = t & 63;
    const int lr   = lane & 15;
    const int lg   = lane >> 4;

    if (t < 128) sw[t]       = ob1[t];
    if (t < 64)  sw[128 + t] = ob2[t];
    if (t < 32)  sw[192 + t] = ob3[t];
    if (t < 16)  sw[224 + t] = ob4[t];
    if (t < 8)   sw[240 + t] = rb1[t];
    if (t < 4)   sw[248 + t] = rb2[t];
    if (t < 50)  sw[252 + t] = rb3[t];
    if (t < 128) sw[302 + t] = rw1[t];
    if (t < 32)  sw[430 + t] = rw2[t];
    if (t < 200) sw[462 + t] = rw3[t];

    short8 w2f[4];
#pragma unroll
    for (int kt = 0; kt < 4; ++kt)
        w2f[kt] = load_wfrag(ow2, w * 16 + lr, 128, kt * 32 + lg * 8);

    short8 w3f[2][2];
#pragma unroll
    for (int mt = 0; mt < 2; ++mt)
#pragma unroll
        for (int kt = 0; kt < 2; ++kt)
            w3f[mt][kt] = load_wfrag(ow3, mt * 16 + lr, 64, kt * 32 + lg * 8);

    short8 w4f = load_wfrag(ow4, lr, 32, lg * 8);

    __syncthreads();   // sw ready

    const int e = t >> 2, p = t & 3;
    short8 vl0, vl1, vl2, vl3, vr0, vr1, vr2, vr3;

#define LOADTILE(TI)                                                        \
    {                                                                       \
        int eg  = (TI) * 64 + e;                                            \
        int egc = eg < N_EDGES ? eg : N_EDGES - 1;                          \
        int sn = src[egc], dn = dst[egc];                                   \
        const short8* plp = (const short8*)(plb + (size_t)sn * 128 + p * 32); \
        const short8* prp = (const short8*)(prb + (size_t)dn * 128 + p * 32); \
        vl0 = plp[0]; vl1 = plp[1]; vl2 = plp[2]; vl3 = plp[3];             \
        vr0 = prp[0]; vr1 = prp[1]; vr2 = prp[2]; vr3 = prp[3];             \
    }

    LOADTILE(blockIdx.x)

    for (int tile = blockIdx.x; tile < NTILES; tile += EBLOCKS) {
        const int base = tile * 64;

        // ---- stage a1 = relu(PL[src] + PR[dst] + ob1), bf16, swizzled ----
        {
            short8 VL[4] = {vl0, vl1, vl2, vl3};
            short8 VR[4] = {vr0, vr1, vr2, vr3};
#pragma unroll
            for (int j = 0; j < 4; ++j) {
                short8 s;
#pragma unroll
                for (int i = 0; i < 8; ++i) {
                    float v = bf2f(VL[j][i]) + bf2f(VR[j][i]) + sw[p * 32 + j * 8 + i];
                    s[i] = f2bf(v > 0.0f ? v : 0.0f);
                }
                int scol = (p * 32 + j * 8) ^ ((e & 7) << 3);
                *(short8*)&a1s[e * 128 + scol] = s;
            }
        }
        __syncthreads();

        // ---- prefetch next tile (flies during L2 + tail) ----
        if (tile + EBLOCKS < NTILES) LOADTILE(tile + EBLOCKS)

        // ---- L2: 128 -> 64, relu ----
        {
            f32x4 acc[4];
            f32x4 bia;
#pragma unroll
            for (int r = 0; r < 4; ++r) bia[r] = sw[128 + w * 16 + lg * 4 + r];
#pragma unroll
            for (int nt = 0; nt < 4; ++nt) acc[nt] = bia;
#pragma unroll
            for (int kt = 0; kt < 4; ++kt) {
#pragma unroll
                for (int nt = 0; nt < 4; ++nt) {
                    int en = nt * 16 + lr;
                    int scol = (kt * 32 + lg * 8) ^ ((en & 7) << 3);
                    short8 bf = *(const short8*)&a1s[en * 128 + scol];
                    acc[nt] = MFMA16(w2f[kt], bf, acc[nt]);
                }
            }
#pragma unroll
            for (int nt = 0; nt < 4; ++nt) {
                int en = nt * 16 + lr;
                int n0 = w * 16 + lg * 4;
                short4v s;
#pragma unroll
                for (int r = 0; r < 4; ++r) {
                    float v = acc[nt][r];
                    s[r] = f2bf(v > 0.0f ? v : 0.0f);
                }
                *(short4v*)&act2[en * 64 + (n0 ^ ((en & 7) << 3))] = s;
            }
        }
        __syncthreads();   // act2 ready; a1s dead -> tail T may alias

        // ---- wave-local tail: L3, L4, rf1, rf2, rf3 ----
        {
            const int e3 = w * 16 + lr;
            float* T = tailf + w * 512;

            f32x4 acc[2];
#pragma unroll
            for (int mt = 0; mt < 2; ++mt)
#pragma unroll
                for (int r = 0; r < 4; ++r) acc[mt][r] = sw[192 + mt * 16 + lg * 4 + r];
#pragma unroll
            for (int kt = 0; kt < 2; ++kt) {
                int scol = (kt * 32 + lg * 8) ^ ((e3 & 7) << 3);
                short8 bf = *(const short8*)&act2[e3 * 64 + scol];
#pragma unroll
                for (int mt = 0; mt < 2; ++mt)
                    acc[mt] = MFMA16(w3f[mt][kt], bf, acc[mt]);
            }
#pragma unroll
            for (int mt = 0; mt < 2; ++mt) {
                short4v s;
#pragma unroll
                for (int r = 0; r < 4; ++r) {
                    float v = acc[mt][r];
                    s[r] = f2bf(v > 0.0f ? v : 0.0f);
                }
                *(short4v*)&act3[e3 * 32 + mt * 16 + lg * 4] = s;
            }
            __builtin_amdgcn_wave_barrier();

            {
                short8 bf = *(const short8*)&act3[e3 * 32 + lg * 8];
                f32x4 a4;
#pragma unroll
                for (int r = 0; r < 4; ++r) a4[r] = sw[224 + lg * 4 + r];
                a4 = MFMA16(w4f, bf, a4);
#pragma unroll
                for (int r = 0; r < 4; ++r) T[lr * 17 + lg * 4 + r] = a4[r];
            }
            __builtin_amdgcn_wave_barrier();

            {
                float af[16];
#pragma unroll
                for (int f = 0; f < 16; ++f) af[f] = T[lr * 17 + f];
#pragma unroll
                for (int oo = 0; oo < 2; ++oo) {
                    int o = lg * 2 + oo;
                    float v = sw[240 + o];
#pragma unroll
                    for (int f = 0; f < 16; ++f) v += af[f] * sw[302 + o * 16 + f];
                    T[272 + lr * 9 + o] = v > 0.0f ? v : 0.0f;
                }
            }
            __builtin_amdgcn_wave_barrier();

            {
                float v = sw[248 + lg];
#pragma unroll
                for (int f = 0; f < 8; ++f) v += T[272 + lr * 9 + f] * sw[430 + lg * 8 + f];
                T[416 + lr * 5 + lg] = v > 0.0f ? v : 0.0f;
            }
            __builtin_amdgcn_wave_barrier();

            // rf3: 4 -> 50, per-wave coalesced (3200 B contiguous, 128B-aligned)
            size_t obase = (size_t)(base + w * 16) * N_REL;
#pragma unroll
            for (int k2 = 0; k2 < 13; ++k2) {
                int idx = k2 * 64 + lane;
                if (idx < 16 * N_REL) {
                    int el = idx / N_REL;
                    int o  = idx - el * N_REL;
                    if (base + w * 16 + el < N_EDGES) {
                        float v = sw[252 + o];
#pragma unroll
                        for (int f = 0; f < 4; ++f) v += T[416 + el * 5 + f] * sw[462 + o * 4 + f];
                        out[obase + idx] = v;
                    }
                }
            }
        }
        __syncthreads();
    }
#undef LOADTILE
}

extern "C" void kernel_launch(void* const* d_in, const int* in_sizes, int n_in,
                              void* d_out, int out_size, void* d_ws, size_t ws_size,
                              hipStream_t stream) {
    const float* x    = (const float*)d_in[0];
    const int*   ei   = (const int*)d_in[1];
    const int*   src  = ei;
    const int*   dst  = ei + N_EDGES;
    const int*   y    = (const int*)d_in[2];
    const float* w1_l = (const float*)d_in[3];
    const float* b1   = (const float*)d_in[4];
    const float* w1_r = (const float*)d_in[5];
    const float* w2_l = (const float*)d_in[6];
    const float* b2   = (const float*)d_in[7];
    const float* w2_r = (const float*)d_in[8];
    const float* ow1  = (const float*)d_in[9];
    const float* ob1  = (const float*)d_in[10];
    const float* ow2  = (const float*)d_in[11];
    const float* ob2  = (const float*)d_in[12];
    const float* ow3  = (const float*)d_in[13];
    const float* ob3  = (const float*)d_in[14];
    const float* ow4  = (const float*)d_in[15];
    const float* ob4  = (const float*)d_in[16];
    const float* rw1  = (const float*)d_in[17];
    const float* rb1  = (const float*)d_in[18];
    const float* rw2  = (const float*)d_in[19];
    const float* rb2  = (const float*)d_in[20];
    const float* rw3  = (const float*)d_in[21];
    const float* rb3  = (const float*)d_in[22];

    float* ws     = (float*)d_ws;
    int*   cnt_i  = (int*)(ws + CNTI_OFF);
    int*   starts = (int*)(ws + STARTS_OFF);
    int*   cursor = (int*)(ws + CURSOR_OFF);
    int*   srcb   = (int*)(ws + SRCB_OFF);
    short* prb    = (short*)(ws + PRB_OFF);
    short* h1b    = (short*)(ws + H1_OFF);
    short* plb    = (short*)(ws + PLB_OFF);
    float* out    = (float*)d_out;

    hipMemsetAsync(cnt_i, 0, N_NODES * sizeof(int), stream);

    k_histy <<<(N_EDGES + 255) / 256, 256, 0, stream>>>(dst, cnt_i, y, out);
    k_scan  <<<1, 1024, 0, stream>>>(cnt_i, starts, cursor);
    k_bucket<<<(N_EDGES + 255) / 256, 256, 0, stream>>>(src, dst, cursor, srcb);

    k_sage1g<<<NODE_TILES, 256, 0, stream>>>(x, srcb, starts, cnt_i, w1_l, b1, w1_r, h1b);
    k_sage2g<<<NODE_TILES, 256, 0, stream>>>(h1b, srcb, starts, cnt_i,
                                             w2_l, b2, w2_r, ow1, plb, prb);

    k_edge3<<<EBLOCKS, 256, 0, stream>>>(
        plb, prb, src, dst,
        ob1, ow2, ob2, ow3, ob3, ow4, ob4,
        rw1, rb1, rw2, rb2, rw3, rb3, out);
}

// Round 12
// 404.431 us; speedup vs baseline: 1.0988x; 1.0004x over previous
//
#include <hip/hip_runtime.h>
#include <hip/hip_bf16.h>

#define N_NODES 50000
#define N_EDGES 500000
#define N_REL   50
#define NTILES  ((N_EDGES + 63) / 64)   // 7813
#define EBLOCKS 1024
#define NODE_TILES ((N_NODES + 63) / 64)  // 782

// workspace layout (float-sized slots)
#define CNTI_OFF   0                          // int[50000]  (memset to 0)
#define STARTS_OFF (CNTI_OFF + N_NODES)
#define CURSOR_OFF (STARTS_OFF + N_NODES)
#define SRCB_OFF   (CURSOR_OFF + N_NODES)     // int[500000] src grouped by dst
#define PRB_OFF    (SRCB_OFF + N_EDGES)       // short[50000*128] (bf16)
#define H1_OFF     (PRB_OFF + N_NODES*32)     // short[50000*64]  (bf16)
#define PLB_OFF    (H1_OFF + N_NODES*32)      // short[50000*128] (bf16)
// end = PLB_OFF + N_NODES*32 = 8.65M floats = 34.6 MB

typedef short short8  __attribute__((ext_vector_type(8)));
typedef short short4v __attribute__((ext_vector_type(4)));
typedef float f32x4   __attribute__((ext_vector_type(4)));
typedef float f4      __attribute__((ext_vector_type(4)));

#define MFMA16(a,b,c) __builtin_amdgcn_mfma_f32_16x16x32_bf16((a),(b),(c),0,0,0)

__device__ __forceinline__ short f2bf(float x) {
    unsigned u = __float_as_uint(x);
    unsigned r = (u + 0x7fffu + ((u >> 16) & 1u)) >> 16;   // RNE
    return (short)r;
}
__device__ __forceinline__ float bf2f(short s) {
    return __uint_as_float(((unsigned)(unsigned short)s) << 16);
}

__device__ __forceinline__ short8 load_wfrag(const float* __restrict__ W, int row, int K, int k) {
    const f4* p = (const f4*)(W + (size_t)row * K + k);
    f4 a = p[0], b = p[1];
    short8 r;
    r[0] = f2bf(a[0]); r[1] = f2bf(a[1]); r[2] = f2bf(a[2]); r[3] = f2bf(a[3]);
    r[4] = f2bf(b[0]); r[5] = f2bf(b[1]); r[6] = f2bf(b[2]); r[7] = f2bf(b[3]);
    return r;
}

// ---------------- CSR build ----------------

__global__ __launch_bounds__(256) void k_histy(
    const int* __restrict__ dst, int* __restrict__ cnt_i,
    const int* __restrict__ y, float* __restrict__ out)
{
    int e = blockIdx.x * blockDim.x + threadIdx.x;
    if (e < N_EDGES) {
        atomicAdd(&cnt_i[dst[e]], 1);
        out[(size_t)N_EDGES * N_REL + e] = (float)y[e];
    }
}

__global__ __launch_bounds__(1024) void k_scan(
    const int* __restrict__ cnt_i, int* __restrict__ starts, int* __restrict__ cursor)
{
    __shared__ int part[1024];
    const int i  = threadIdx.x;
    const int lo = i * 49;
    const int hi = min(N_NODES, lo + 49);
    int s = 0;
    for (int j = lo; j < hi; ++j) s += cnt_i[j];
    part[i] = s;
    __syncthreads();
    for (int d = 1; d < 1024; d <<= 1) {
        int v = (i >= d) ? part[i - d] : 0;
        __syncthreads();
        part[i] += v;
        __syncthreads();
    }
    int off = (i == 0) ? 0 : part[i - 1];
    for (int j = lo; j < hi; ++j) {
        starts[j] = off;
        cursor[j] = off;
        off += cnt_i[j];
    }
}

__global__ __launch_bounds__(256) void k_bucket(
    const int* __restrict__ src, const int* __restrict__ dst,
    int* __restrict__ cursor, int* __restrict__ srcb)
{
    int e = blockIdx.x * blockDim.x + threadIdx.x;
    if (e < N_EDGES) {
        int pos = atomicAdd(&cursor[dst[e]], 1);
        srcb[pos] = src[e];
    }
}

// ---------------- SAGE1 with fused in-edge gather (unchanged) ----------------
__global__ __launch_bounds__(256) void k_sage1g(
    const float* __restrict__ x, const int* __restrict__ srcb,
    const int* __restrict__ starts, const int* __restrict__ cnt_i,
    const float* __restrict__ w1_l, const float* __restrict__ b1,
    const float* __restrict__ w1_r, short* __restrict__ h1b)
{
    __shared__ short feat[64 * 40];

    const int t    = threadIdx.x;
    const int w    = t >> 6;
    const int lane = t & 63;
    const int lr   = lane & 15;
    const int lg   = lane >> 4;
    const int base = blockIdx.x * 64;

    short8 w1f;
    if (lg < 2) w1f = load_wfrag(w1_l, w * 16 + lr, 16, lg * 8);
    else        w1f = load_wfrag(w1_r, w * 16 + lr, 16, (lg - 2) * 8);

    {
        int e  = t >> 2, q = t & 3;
        int ng = base + e;
        short8 v = (short8)0;
        if (ng < N_NODES) {
            if (q < 2) {
                int st = starts[ng], c = cnt_i[ng];
                float acc[8] = {0, 0, 0, 0, 0, 0, 0, 0};
                for (int i = 0; i < c; ++i) {
                    const float* xp = x + (size_t)srcb[st + i] * 16 + q * 8;
                    f4 a = *(const f4*)xp;
                    f4 b = *(const f4*)(xp + 4);
#pragma unroll
                    for (int j = 0; j < 4; ++j) { acc[j] += a[j]; acc[4 + j] += b[j]; }
                }
                float inv = 1.0f / (float)(c > 0 ? c : 1);
#pragma unroll
                for (int j = 0; j < 8; ++j) v[j] = f2bf(acc[j] * inv);
            } else {
                f4 a = *(const f4*)(x + (size_t)ng * 16 + (q - 2) * 8);
                f4 b = *(const f4*)(x + (size_t)ng * 16 + (q - 2) * 8 + 4);
#pragma unroll
                for (int j = 0; j < 4; ++j) { v[j] = f2bf(a[j]); v[4 + j] = f2bf(b[j]); }
            }
        }
        *(short8*)&feat[e * 40 + q * 8] = v;
    }
    __syncthreads();

    f32x4 acc[4];
    f4 bia = *(const f4*)&b1[w * 16 + lg * 4];
#pragma unroll
    for (int nt = 0; nt < 4; ++nt) {
        acc[nt][0] = bia[0]; acc[nt][1] = bia[1]; acc[nt][2] = bia[2]; acc[nt][3] = bia[3];
    }
#pragma unroll
    for (int nt = 0; nt < 4; ++nt) {
        int e = nt * 16 + lr;
        short8 bf = *(const short8*)&feat[e * 40 + lg * 8];
        acc[nt] = MFMA16(w1f, bf, acc[nt]);
    }
#pragma unroll
    for (int nt = 0; nt < 4; ++nt) {
        int ng = base + nt * 16 + lr;
        if (ng < N_NODES) {
            short4v o;
#pragma unroll
            for (int r = 0; r < 4; ++r) { float v = acc[nt][r]; o[r] = f2bf(v > 0.0f ? v : 0.0f); }
            *(short4v*)&h1b[(size_t)ng * 64 + w * 16 + lg * 4] = o;
        }
    }
}

// ---------------- SAGE2 + proj, 512 threads, 8-way-parallel gather ----------
// Staging thread (e = t>>3, q = t&7): half = q&1 (32 feats), par = q>>1
// (edges i%4==par). Partials combined in-register via __shfl_xor butterfly
// (masks 2,4 — the 8 node-threads are wave-adjacent lanes). par==0 lanes
// write the mean (K slots [64,128)); q in {2,3} lanes stage self-h1
// (K slots [0,64)). MFMA phase A: wave w owns out rows [w*16, w*16+16).
// Phase B: waves 0-3 own PL rows [(w&3)*32, +32), waves 4-7 own PR.
__global__ __launch_bounds__(512, 4) void k_sage2g(
    const short* __restrict__ h1b, const int* __restrict__ srcb,
    const int* __restrict__ starts, const int* __restrict__ cnt_i,
    const float* __restrict__ w2_l, const float* __restrict__ b2,
    const float* __restrict__ w2_r, const float* __restrict__ ow1,
    short* __restrict__ plb, short* __restrict__ prb)
{
    __shared__ short feat[64 * 128];
    __shared__ short feat2[64 * 128];

    const int t    = threadIdx.x;
    const int w    = t >> 6;           // wave 0..7
    const int lane = t & 63;
    const int lr   = lane & 15;
    const int lg   = lane >> 4;
    const int base = blockIdx.x * 64;

    // phase-A fragments: wave w owns out rows [w*16, w*16+16)
    short8 wf[4];
#pragma unroll
    for (int kt = 0; kt < 4; ++kt) {
        int row = w * 16 + lr;
        int k   = kt * 32 + lg * 8;
        wf[kt] = (k < 64) ? load_wfrag(w2_r, row, 64, k)
                          : load_wfrag(w2_l, row, 64, k - 64);
    }

    // ---- staging: 8 threads per node ----
    {
        int e    = t >> 3;             // node-local 0..63
        int q    = t & 7;
        int half = q & 1;              // feat half (32 feats)
        int par  = q >> 1;             // edge residue mod 4
        int ng   = base + e;
        float acc[32];
#pragma unroll
        for (int j = 0; j < 32; ++j) acc[j] = 0.0f;
        int c = 0;
        if (ng < N_NODES) {
            int st = starts[ng];
            c = cnt_i[ng];
            for (int i = par; i < c; i += 4) {
                const short8* hp = (const short8*)(h1b + (size_t)srcb[st + i] * 64 + half * 32);
                short8 a0 = hp[0], a1 = hp[1], a2 = hp[2], a3 = hp[3];
#pragma unroll
                for (int j = 0; j < 8; ++j) {
                    acc[j]      += bf2f(a0[j]);
                    acc[8 + j]  += bf2f(a1[j]);
                    acc[16 + j] += bf2f(a2[j]);
                    acc[24 + j] += bf2f(a3[j]);
                }
            }
        }
        // butterfly over the 4 parities (lane bits 1,2); halves (bit 0) stay separate
#pragma unroll
        for (int j = 0; j < 32; ++j) {
            float v = acc[j];
            v += __shfl_xor(v, 2);
            v += __shfl_xor(v, 4);
            acc[j] = v;
        }
        if (par == 0) {
            float inv = 1.0f / (float)(c > 0 ? c : 1);
#pragma unroll
            for (int jj = 0; jj < 4; ++jj) {
                short8 v;
#pragma unroll
                for (int j = 0; j < 8; ++j) v[j] = f2bf(acc[jj * 8 + j] * inv);
                int scol = (half * 32 + 64 + jj * 8) ^ ((e & 7) << 3);
                *(short8*)&feat[e * 128 + scol] = v;
            }
        } else if (q == 2 || q == 3) {
            int hs = q - 2;
            const short* hp = (ng < N_NODES) ? (h1b + (size_t)ng * 64 + hs * 32) : nullptr;
#pragma unroll
            for (int j = 0; j < 4; ++j) {
                short8 v = hp ? *(const short8*)(hp + j * 8) : (short8)0;
                int scol = (hs * 32 + j * 8) ^ ((e & 7) << 3);
                *(short8*)&feat[e * 128 + scol] = v;
            }
        }
    }
    __syncthreads();   // feat ready

    // phase A: h2 tile (bf16, swizzled, LDS only); wave w -> 16 out rows
    {
        f32x4 acc[4];
        f4 bia = *(const f4*)&b2[w * 16 + lg * 4];
#pragma unroll
        for (int nt = 0; nt < 4; ++nt) {
            acc[nt][0] = bia[0]; acc[nt][1] = bia[1];
            acc[nt][2] = bia[2]; acc[nt][3] = bia[3];
        }
#pragma unroll
        for (int kt = 0; kt < 4; ++kt) {
            short8 bf[4];
#pragma unroll
            for (int nt = 0; nt < 4; ++nt) {
                int e = nt * 16 + lr;
                int scol = (kt * 32 + lg * 8) ^ ((e & 7) << 3);
                bf[nt] = *(const short8*)&feat[e * 128 + scol];
            }
#pragma unroll
            for (int nt = 0; nt < 4; ++nt)
                acc[nt] = MFMA16(wf[kt], bf[nt], acc[nt]);
        }
#pragma unroll
        for (int nt = 0; nt < 4; ++nt) {
            int e  = nt * 16 + lr;
            int n0 = w * 16 + lg * 4;
            short4v s;
#pragma unroll
            for (int r = 0; r < 4; ++r) {
                float v = acc[nt][r];
                s[r] = f2bf(v > 0.0f ? v : 0.0f);
            }
            *(short4v*)&feat2[e * 128 + (n0 ^ ((e & 7) << 3))] = s;
        }
    }
    __syncthreads();

    // phase B: PL (waves 0-3) / PR (waves 4-7) projections
    {
        const int isR = (w >= 4);
        const int wb  = w & 3;
        short8 wfp[2][4];
#pragma unroll
        for (int mt = 0; mt < 2; ++mt)
#pragma unroll
            for (int kt = 0; kt < 4; ++kt) {
                int row = wb * 32 + mt * 16 + lr;
                int k   = kt * 32 + lg * 8 + (isR ? 128 : 0);
                wfp[mt][kt] = load_wfrag(ow1, row, 256, k);
            }
        f32x4 ap[2][4];
#pragma unroll
        for (int mt = 0; mt < 2; ++mt)
#pragma unroll
            for (int nt = 0; nt < 4; ++nt) ap[mt][nt] = (f32x4)0.0f;
#pragma unroll
        for (int kt = 0; kt < 4; ++kt) {
            short8 bf[4];
#pragma unroll
            for (int nt = 0; nt < 4; ++nt) {
                int e = nt * 16 + lr;
                int scol = (kt * 32 + lg * 8) ^ ((e & 7) << 3);
                bf[nt] = *(const short8*)&feat2[e * 128 + scol];
            }
#pragma unroll
            for (int mt = 0; mt < 2; ++mt)
#pragma unroll
                for (int nt = 0; nt < 4; ++nt)
                    ap[mt][nt] = MFMA16(wfp[mt][kt], bf[nt], ap[mt][nt]);
        }
        short* outp = isR ? prb : plb;
#pragma unroll
        for (int mt = 0; mt < 2; ++mt)
#pragma unroll
            for (int nt = 0; nt < 4; ++nt) {
                int ng = base + nt * 16 + lr;
                if (ng < N_NODES) {
                    int n0 = wb * 32 + mt * 16 + lg * 4;
                    short4v o;
#pragma unroll
                    for (int r = 0; r < 4; ++r) o[r] = f2bf(ap[mt][nt][r]);
                    *(short4v*)&outp[(size_t)ng * 128 + n0] = o;
                }
            }
    }
}

// ---------------- edge MLP v3 (R7 config, unchanged): prefetch, per-wave tail
__global__ __launch_bounds__(256, 4) void k_edge3(
    const short* __restrict__ plb, const short* __restrict__ prb,
    const int* __restrict__ src, const int* __restrict__ dst,
    const float* __restrict__ ob1,
    const float* __restrict__ ow2, const float* __restrict__ ob2,
    const float* __restrict__ ow3, const float* __restrict__ ob3,
    const float* __restrict__ ow4, const float* __restrict__ ob4,
    const float* __restrict__ rw1, const float* __restrict__ rb1,
    const float* __restrict__ rw2, const float* __restrict__ rb2,
    const float* __restrict__ rw3, const float* __restrict__ rb3,
    float* __restrict__ out)
{
    __shared__ short a1s[64 * 128];    // 16KB; tail T aliases
    __shared__ short actB[64 * 96];    // act2 | act3
    __shared__ float sw[662];

    short* act2  = actB;
    short* act3  = actB + 64 * 64;
    float* tailf = (float*)a1s;        // T region: wave w uses [w*512, w*512+512)

    const int t    = threadIdx.x;
    const int w    = t >> 6;
    const int lane = t & 63;
    const int lr   = lane & 15;
    const int lg   = lane >> 4;

    if (t < 128) sw[t]       = ob1[t];
    if (t < 64)  sw[128 + t] = ob2[t];
    if (t < 32)  sw[192 + t] = ob3[t];
    if (t < 16)  sw[224 + t] = ob4[t];
    if (t < 8)   sw[240 + t] = rb1[t];
    if (t < 4)   sw[248 + t] = rb2[t];
    if (t < 50)  sw[252 + t] = rb3[t];
    if (t < 128) sw[302 + t] = rw1[t];
    if (t < 32)  sw[430 + t] = rw2[t];
    if (t < 200) sw[462 + t] = rw3[t];

    short8 w2f[4];
#pragma unroll
    for (int kt = 0; kt < 4; ++kt)
        w2f[kt] = load_wfrag(ow2, w * 16 + lr, 128, kt * 32 + lg * 8);

    short8 w3f[2][2];
#pragma unroll
    for (int mt = 0; mt < 2; ++mt)
#pragma unroll
        for (int kt = 0; kt < 2; ++kt)
            w3f[mt][kt] = load_wfrag(ow3, mt * 16 + lr, 64, kt * 32 + lg * 8);

    short8 w4f = load_wfrag(ow4, lr, 32, lg * 8);

    __syncthreads();   // sw ready

    const int e = t >> 2, p = t & 3;
    short8 vl0, vl1, vl2, vl3, vr0, vr1, vr2, vr3;

#define LOADTILE(TI)                                                        \
    {                                                                       \
        int eg  = (TI) * 64 + e;                                            \
        int egc = eg < N_EDGES ? eg : N_EDGES - 1;                          \
        int sn = src[egc], dn = dst[egc];                                   \
        const short8* plp = (const short8*)(plb + (size_t)sn * 128 + p * 32); \
        const short8* prp = (const short8*)(prb + (size_t)dn * 128 + p * 32); \
        vl0 = plp[0]; vl1 = plp[1]; vl2 = plp[2]; vl3 = plp[3];             \
        vr0 = prp[0]; vr1 = prp[1]; vr2 = prp[2]; vr3 = prp[3];             \
    }

    LOADTILE(blockIdx.x)

    for (int tile = blockIdx.x; tile < NTILES; tile += EBLOCKS) {
        const int base = tile * 64;

        // ---- stage a1 = relu(PL[src] + PR[dst] + ob1), bf16, swizzled ----
        {
            short8 VL[4] = {vl0, vl1, vl2, vl3};
            short8 VR[4] = {vr0, vr1, vr2, vr3};
#pragma unroll
            for (int j = 0; j < 4; ++j) {
                short8 s;
#pragma unroll
                for (int i = 0; i < 8; ++i) {
                    float v = bf2f(VL[j][i]) + bf2f(VR[j][i]) + sw[p * 32 + j * 8 + i];
                    s[i] = f2bf(v > 0.0f ? v : 0.0f);
                }
                int scol = (p * 32 + j * 8) ^ ((e & 7) << 3);
                *(short8*)&a1s[e * 128 + scol] = s;
            }
        }
        __syncthreads();

        // ---- prefetch next tile (flies during L2 + tail) ----
        if (tile + EBLOCKS < NTILES) LOADTILE(tile + EBLOCKS)

        // ---- L2: 128 -> 64, relu ----
        {
            f32x4 acc[4];
            f32x4 bia;
#pragma unroll
            for (int r = 0; r < 4; ++r) bia[r] = sw[128 + w * 16 + lg * 4 + r];
#pragma unroll
            for (int nt = 0; nt < 4; ++nt) acc[nt] = bia;
#pragma unroll
            for (int kt = 0; kt < 4; ++kt) {
#pragma unroll
                for (int nt = 0; nt < 4; ++nt) {
                    int en = nt * 16 + lr;
                    int scol = (kt * 32 + lg * 8) ^ ((en & 7) << 3);
                    short8 bf = *(const short8*)&a1s[en * 128 + scol];
                    acc[nt] = MFMA16(w2f[kt], bf, acc[nt]);
                }
            }
#pragma unroll
            for (int nt = 0; nt < 4; ++nt) {
                int en = nt * 16 + lr;
                int n0 = w * 16 + lg * 4;
                short4v s;
#pragma unroll
                for (int r = 0; r < 4; ++r) {
                    float v = acc[nt][r];
                    s[r] = f2bf(v > 0.0f ? v : 0.0f);
                }
                *(short4v*)&act2[en * 64 + (n0 ^ ((en & 7) << 3))] = s;
            }
        }
        __syncthreads();   // act2 ready; a1s dead -> tail T may alias

        // ---- wave-local tail: L3, L4, rf1, rf2, rf3 ----
        {
            const int e3 = w * 16 + lr;
            float* T = tailf + w * 512;

            f32x4 acc[2];
#pragma unroll
            for (int mt = 0; mt < 2; ++mt)
#pragma unroll
                for (int r = 0; r < 4; ++r) acc[mt][r] = sw[192 + mt * 16 + lg * 4 + r];
#pragma unroll
            for (int kt = 0; kt < 2; ++kt) {
                int scol = (kt * 32 + lg * 8) ^ ((e3 & 7) << 3);
                short8 bf = *(const short8*)&act2[e3 * 64 + scol];
#pragma unroll
                for (int mt = 0; mt < 2; ++mt)
                    acc[mt] = MFMA16(w3f[mt][kt], bf, acc[mt]);
            }
#pragma unroll
            for (int mt = 0; mt < 2; ++mt) {
                short4v s;
#pragma unroll
                for (int r = 0; r < 4; ++r) {
                    float v = acc[mt][r];
                    s[r] = f2bf(v > 0.0f ? v : 0.0f);
                }
                *(short4v*)&act3[e3 * 32 + mt * 16 + lg * 4] = s;
            }
            __builtin_amdgcn_wave_barrier();

            {
                short8 bf = *(const short8*)&act3[e3 * 32 + lg * 8];
                f32x4 a4;
#pragma unroll
                for (int r = 0; r < 4; ++r) a4[r] = sw[224 + lg * 4 + r];
                a4 = MFMA16(w4f, bf, a4);
#pragma unroll
                for (int r = 0; r < 4; ++r) T[lr * 17 + lg * 4 + r] = a4[r];
            }
            __builtin_amdgcn_wave_barrier();

            {
                float af[16];
#pragma unroll
                for (int f = 0; f < 16; ++f) af[f] = T[lr * 17 + f];
#pragma unroll
                for (int oo = 0; oo < 2; ++oo) {
                    int o = lg * 2 + oo;
                    float v = sw[240 + o];
#pragma unroll
                    for (int f = 0; f < 16; ++f) v += af[f] * sw[302 + o * 16 + f];
                    T[272 + lr * 9 + o] = v > 0.0f ? v : 0.0f;
                }
            }
            __builtin_amdgcn_wave_barrier();

            {
                float v = sw[248 + lg];
#pragma unroll
                for (int f = 0; f < 8; ++f) v += T[272 + lr * 9 + f] * sw[430 + lg * 8 + f];
                T[416 + lr * 5 + lg] = v > 0.0f ? v : 0.0f;
            }
            __builtin_amdgcn_wave_barrier();

            // rf3: 4 -> 50, per-wave coalesced (3200 B contiguous)
            size_t obase = (size_t)(base + w * 16) * N_REL;
#pragma unroll
            for (int k2 = 0; k2 < 13; ++k2) {
                int idx = k2 * 64 + lane;
                if (idx < 16 * N_REL) {
                    int el = idx / N_REL;
                    int o  = idx - el * N_REL;
                    if (base + w * 16 + el < N_EDGES) {
                        float v = sw[252 + o];
#pragma unroll
                        for (int f = 0; f < 4; ++f) v += T[416 + el * 5 + f] * sw[462 + o * 4 + f];
                        out[obase + idx] = v;
                    }
                }
            }
        }
        __syncthreads();
    }
#undef LOADTILE
}

extern "C" void kernel_launch(void* const* d_in, const int* in_sizes, int n_in,
                              void* d_out, int out_size, void* d_ws, size_t ws_size,
                              hipStream_t stream) {
    const float* x    = (const float*)d_in[0];
    const int*   ei   = (const int*)d_in[1];
    const int*   src  = ei;
    const int*   dst  = ei + N_EDGES;
    const int*   y    = (const int*)d_in[2];
    const float* w1_l = (const float*)d_in[3];
    const float* b1   = (const float*)d_in[4];
    const float* w1_r = (const float*)d_in[5];
    const float* w2_l = (const float*)d_in[6];
    const float* b2   = (const float*)d_in[7];
    const float* w2_r = (const float*)d_in[8];
    const float* ow1  = (const float*)d_in[9];
    const float* ob1  = (const float*)d_in[10];
    const float* ow2  = (const float*)d_in[11];
    const float* ob2  = (const float*)d_in[12];
    const float* ow3  = (const float*)d_in[13];
    const float* ob3  = (const float*)d_in[14];
    const float* ow4  = (const float*)d_in[15];
    const float* ob4  = (const float*)d_in[16];
    const float* rw1  = (const float*)d_in[17];
    const float* rb1  = (const float*)d_in[18];
    const float* rw2  = (const float*)d_in[19];
    const float* rb2  = (const float*)d_in[20];
    const float* rw3  = (const float*)d_in[21];
    const float* rb3  = (const float*)d_in[22];

    float* ws     = (float*)d_ws;
    int*   cnt_i  = (int*)(ws + CNTI_OFF);
    int*   starts = (int*)(ws + STARTS_OFF);
    int*   cursor = (int*)(ws + CURSOR_OFF);
    int*   srcb   = (int*)(ws + SRCB_OFF);
    short* prb    = (short*)(ws + PRB_OFF);
    short* h1b    = (short*)(ws + H1_OFF);
    short* plb    = (short*)(ws + PLB_OFF);
    float* out    = (float*)d_out;

    hipMemsetAsync(cnt_i, 0, N_NODES * sizeof(int), stream);

    k_histy <<<(N_EDGES + 255) / 256, 256, 0, stream>>>(dst, cnt_i, y, out);
    k_scan  <<<1, 1024, 0, stream>>>(cnt_i, starts, cursor);
    k_bucket<<<(N_EDGES + 255) / 256, 256, 0, stream>>>(src, dst, cursor, srcb);

    k_sage1g<<<NODE_TILES, 256, 0, stream>>>(x, srcb, starts, cnt_i, w1_l, b1, w1_r, h1b);
    k_sage2g<<<NODE_TILES, 512, 0, stream>>>(h1b, srcb, starts, cnt_i,
                                             w2_l, b2, w2_r, ow1, plb, prb);

    k_edge3<<<EBLOCKS, 256, 0, stream>>>(
        plb, prb, src, dst,
        ob1, ow2, ob2, ow3, ob3, ow4, ob4,
        rw1, rb1, rw2, rb2, rw3, rb3, out);
}